// Round 1
// baseline (586.305 us; speedup 1.0000x reference)
//
#include <hip/hip_runtime.h>

// ---------------------------------------------------------------------------
// MultiHeadedAttention forward, bf16 MFMA implementation.
// B=4, T=2048, DIN=DOUT=1024, H=16, HD=64. Causal softmax, eval (no dropout).
// ---------------------------------------------------------------------------

typedef __bf16 bf16_t;
typedef __bf16 bf16x8 __attribute__((ext_vector_type(8)));
typedef float f32x4 __attribute__((ext_vector_type(4)));

#define BB 4
#define TT 2048
#define DK 1024   // DIN = DOUT = 1024
#define NH 16
#define HD 64

static __device__ __forceinline__ f32x4 mfma16(bf16x8 a, bf16x8 b, f32x4 c) {
  return __builtin_amdgcn_mfma_f32_16x16x32_bf16(a, b, c, 0, 0, 0);
}

// ---- cast x (fp32) -> bf16, 8 elems/thread ---------------------------------
__global__ __launch_bounds__(256) void cast_x_kernel(const float* __restrict__ in,
                                                     bf16_t* __restrict__ out, int n8) {
  int i = blockIdx.x * blockDim.x + threadIdx.x;
  if (i < n8) {
    const float4* p = (const float4*)(in + (size_t)i * 8);
    float4 u = p[0], v = p[1];
    bf16x8 o = {(__bf16)u.x, (__bf16)u.y, (__bf16)u.z, (__bf16)u.w,
                (__bf16)v.x, (__bf16)v.y, (__bf16)v.z, (__bf16)v.w};
    *(bf16x8*)(out + (size_t)i * 8) = o;
  }
}

// ---- transpose + cast: W[K][N] fp32 -> Wt[N][K] bf16 (K=N=1024) ------------
__global__ __launch_bounds__(256) void transpose_cast_kernel(const float* __restrict__ W,
                                                             bf16_t* __restrict__ Wt) {
  __shared__ float tile[32][33];
  int bx = blockIdx.x * 32;  // N dim
  int by = blockIdx.y * 32;  // K dim
  int tx = threadIdx.x, ty = threadIdx.y;  // 32 x 8
#pragma unroll
  for (int i = 0; i < 32; i += 8)
    tile[ty + i][tx] = W[(size_t)(by + ty + i) * DK + bx + tx];
  __syncthreads();
#pragma unroll
  for (int i = 0; i < 32; i += 8)
    Wt[(size_t)(bx + ty + i) * DK + by + tx] = (bf16_t)tile[tx][ty + i];
}

// ---- GEMM: C[M][N] = A[M][K] * Bt[N][K]^T, bf16 in, MFMA 16x16x32 ----------
// 64x64 tile, 256 threads = 4 waves (2x2), each wave 32x32 (2x2 fragments).
// MODE 0: store bf16 at [b,h,t,d] (Q,K)     row=b*T+t, col=h*64+d
// MODE 1: store bf16 at [b,h,d,t] (V^T)
// MODE 2: store fp32 + bias at [row][col]   (final output)
template <int MODE>
__global__ __launch_bounds__(256) void gemm_bt(const bf16_t* __restrict__ A,
                                               const bf16_t* __restrict__ Bt,
                                               void* __restrict__ Cout,
                                               const float* __restrict__ bias,
                                               int M, int N, int K) {
  __shared__ __align__(16) bf16_t As[64][40];
  __shared__ __align__(16) bf16_t Bs[64][40];
  const int tid = threadIdx.x;
  const int m0 = blockIdx.y * 64, n0 = blockIdx.x * 64;
  const int w = tid >> 6, lane = tid & 63, g = lane >> 4, r16 = lane & 15;
  const int wr = (w >> 1) * 32, wc = (w & 1) * 32;
  const int sr = tid >> 2, sc = (tid & 3) * 8;  // staging: row, col(8-chunk)

  const bf16_t* Arow = A + (size_t)(m0 + sr) * K + sc;
  const bf16_t* Brow = Bt + (size_t)(n0 + sr) * K + sc;

  f32x4 acc[2][2] = {};

  for (int k0 = 0; k0 < K; k0 += 32) {
    __syncthreads();
    *(bf16x8*)&As[sr][sc] = *(const bf16x8*)(Arow + k0);
    *(bf16x8*)&Bs[sr][sc] = *(const bf16x8*)(Brow + k0);
    __syncthreads();
    bf16x8 a0 = *(bf16x8*)&As[wr + r16][g * 8];
    bf16x8 a1 = *(bf16x8*)&As[wr + 16 + r16][g * 8];
    bf16x8 b0 = *(bf16x8*)&Bs[wc + r16][g * 8];
    bf16x8 b1 = *(bf16x8*)&Bs[wc + 16 + r16][g * 8];
    acc[0][0] = mfma16(a0, b0, acc[0][0]);
    acc[0][1] = mfma16(a0, b1, acc[0][1]);
    acc[1][0] = mfma16(a1, b0, acc[1][0]);
    acc[1][1] = mfma16(a1, b1, acc[1][1]);
  }

#pragma unroll
  for (int m = 0; m < 2; m++)
#pragma unroll
    for (int n = 0; n < 2; n++)
#pragma unroll
      for (int j = 0; j < 4; j++) {
        int row = m0 + wr + m * 16 + g * 4 + j;
        int col = n0 + wc + n * 16 + r16;
        float v = acc[m][n][j];
        if (MODE == 0) {
          int b = row >> 11, t = row & (TT - 1), h = col >> 6, d = col & 63;
          ((bf16_t*)Cout)[(((size_t)(b * NH + h) * TT + t) << 6) + d] = (bf16_t)v;
        } else if (MODE == 1) {
          int b = row >> 11, t = row & (TT - 1), h = col >> 6, d = col & 63;
          ((bf16_t*)Cout)[((size_t)(b * NH + h) * HD + d) * TT + t] = (bf16_t)v;
        } else {
          ((float*)Cout)[(size_t)row * N + col] = v + bias[col];
        }
      }
}

// ---- causal flash attention: 1 wave per 16 q-rows --------------------------
// Q,K: [b,h,t,64] bf16.  Vt: [b,h,64,t] bf16.  ctx out: [b,t,h*64+d] bf16.
__global__ __launch_bounds__(64) void attn_fwd(const bf16_t* __restrict__ Q,
                                               const bf16_t* __restrict__ K,
                                               const bf16_t* __restrict__ Vt,
                                               bf16_t* __restrict__ ctx) {
  const int lane = threadIdx.x, g = lane >> 4, r16 = lane & 15;
  const int q0 = blockIdx.x * 16, bh = blockIdx.y;
  const bf16_t* Qp = Q + (size_t)bh * TT * HD;
  const bf16_t* Kp = K + (size_t)bh * TT * HD;
  const bf16_t* Vp = Vt + (size_t)bh * HD * TT;

  __shared__ __align__(16) bf16_t plds[16][40];

  bf16x8 qf0 = *(const bf16x8*)&Qp[(size_t)(q0 + r16) * HD + g * 8];
  bf16x8 qf1 = *(const bf16x8*)&Qp[(size_t)(q0 + r16) * HD + 32 + g * 8];

  float m_run[4], l_run[4];
  f32x4 o[4] = {};
#pragma unroll
  for (int j = 0; j < 4; j++) { m_run[j] = -1e30f; l_run[j] = 0.f; }

  const int nkt = (q0 + 16 + 31) >> 5;  // 32-key tiles covering keys <= q0+15
  for (int kt = 0; kt < nkt; kt++) {
    const int k0 = kt * 32;
    f32x4 s[2];
#pragma unroll
    for (int h = 0; h < 2; h++) {
      bf16x8 kb0 = *(const bf16x8*)&Kp[(size_t)(k0 + 16 * h + r16) * HD + g * 8];
      bf16x8 kb1 = *(const bf16x8*)&Kp[(size_t)(k0 + 16 * h + r16) * HD + 32 + g * 8];
      f32x4 z = {0.f, 0.f, 0.f, 0.f};
      s[h] = mfma16(qf0, kb0, z);
      s[h] = mfma16(qf1, kb1, s[h]);
    }
    // scale + causal mask
    float p[2][4];
#pragma unroll
    for (int h = 0; h < 2; h++)
#pragma unroll
      for (int j = 0; j < 4; j++) {
        float v = s[h][j] * 0.125f;  // 1/sqrt(64)
        int qg = q0 + g * 4 + j, kg = k0 + 16 * h + r16;
        p[h][j] = (kg <= qg) ? v : -1e30f;
      }
    // online softmax per row (rows live across the 16 lanes of each g-group)
#pragma unroll
    for (int j = 0; j < 4; j++) {
      float t = fmaxf(p[0][j], p[1][j]);
      t = fmaxf(t, __shfl_xor(t, 1));
      t = fmaxf(t, __shfl_xor(t, 2));
      t = fmaxf(t, __shfl_xor(t, 4));
      t = fmaxf(t, __shfl_xor(t, 8));
      float mn = fmaxf(m_run[j], t);
      float fac = __expf(m_run[j] - mn);
      p[0][j] = __expf(p[0][j] - mn);
      p[1][j] = __expf(p[1][j] - mn);
      float rs = p[0][j] + p[1][j];
      rs += __shfl_xor(rs, 1);
      rs += __shfl_xor(rs, 2);
      rs += __shfl_xor(rs, 4);
      rs += __shfl_xor(rs, 8);
      l_run[j] = l_run[j] * fac + rs;
      m_run[j] = mn;
#pragma unroll
      for (int c = 0; c < 4; c++) o[c][j] *= fac;
    }
    // P (C-layout) -> LDS -> A-fragment layout
#pragma unroll
    for (int h = 0; h < 2; h++)
#pragma unroll
      for (int j = 0; j < 4; j++) plds[g * 4 + j][16 * h + r16] = (bf16_t)p[h][j];
    asm volatile("s_waitcnt lgkmcnt(0)" ::: "memory");
    bf16x8 pa = *(bf16x8*)&plds[r16][g * 8];
    // PV: O[16q][64d] += P[16q][32k] * V[32k][64d]
#pragma unroll
    for (int c = 0; c < 4; c++) {
      bf16x8 vb = *(const bf16x8*)&Vp[(size_t)(c * 16 + r16) * TT + k0 + g * 8];
      o[c] = mfma16(pa, vb, o[c]);
    }
  }

  const int b = bh >> 4, h = bh & (NH - 1);
#pragma unroll
  for (int c = 0; c < 4; c++)
#pragma unroll
    for (int j = 0; j < 4; j++) {
      int q = q0 + g * 4 + j, d = c * 16 + r16;
      float val = o[c][j] / l_run[j];
      ctx[((size_t)(b * TT + q)) * DK + h * HD + d] = (bf16_t)val;
    }
}

// ---------------------------------------------------------------------------
extern "C" void kernel_launch(void* const* d_in, const int* in_sizes, int n_in,
                              void* d_out, int out_size, void* d_ws, size_t ws_size,
                              hipStream_t stream) {
  const float* x = (const float*)d_in[0];
  const float* Wq = (const float*)d_in[1];
  const float* Wk = (const float*)d_in[2];
  const float* Wv = (const float*)d_in[3];
  const float* Wo = (const float*)d_in[4];
  const float* bo = (const float*)d_in[5];
  float* out = (float*)d_out;

  char* ws = (char*)d_ws;
  const size_t MB = 1u << 20;
  bf16_t* xb  = (bf16_t*)(ws + 0 * MB);   // 16 MB  [8192][1024]
  bf16_t* Wqt = (bf16_t*)(ws + 16 * MB);  // 2 MB   [1024][1024] (N-major)
  bf16_t* Wkt = (bf16_t*)(ws + 18 * MB);
  bf16_t* Wvt = (bf16_t*)(ws + 20 * MB);
  bf16_t* Wot = (bf16_t*)(ws + 22 * MB);
  bf16_t* Qb  = (bf16_t*)(ws + 24 * MB);  // 16 MB [b,h,t,d]
  bf16_t* Kb  = (bf16_t*)(ws + 40 * MB);  // 16 MB [b,h,t,d]
  bf16_t* Vtb = (bf16_t*)(ws + 56 * MB);  // 16 MB [b,h,d,t]
  bf16_t* ctx = (bf16_t*)(ws + 72 * MB);  // 16 MB [b,t,h*64+d]

  const int M = BB * TT;  // 8192

  cast_x_kernel<<<(M * DK / 8 + 255) / 256, 256, 0, stream>>>(x, xb, M * DK / 8);

  dim3 tb(32, 8), tg(32, 32);
  transpose_cast_kernel<<<tg, tb, 0, stream>>>(Wq, Wqt);
  transpose_cast_kernel<<<tg, tb, 0, stream>>>(Wk, Wkt);
  transpose_cast_kernel<<<tg, tb, 0, stream>>>(Wv, Wvt);
  transpose_cast_kernel<<<tg, tb, 0, stream>>>(Wo, Wot);

  dim3 gg(DK / 64, M / 64);  // (16, 128)
  gemm_bt<0><<<gg, 256, 0, stream>>>(xb, Wqt, Qb, nullptr, M, DK, DK);
  gemm_bt<0><<<gg, 256, 0, stream>>>(xb, Wkt, Kb, nullptr, M, DK, DK);
  gemm_bt<1><<<gg, 256, 0, stream>>>(xb, Wvt, Vtb, nullptr, M, DK, DK);

  attn_fwd<<<dim3(TT / 16, BB * NH), 64, 0, stream>>>(Qb, Kb, Vtb, ctx);

  gemm_bt<2><<<gg, 256, 0, stream>>>(ctx, Wot, out, bo, M, DK, DK);
}

// Round 2
// 456.618 us; speedup vs baseline: 1.2840x; 1.2840x over previous
//
#include <hip/hip_runtime.h>

// ---------------------------------------------------------------------------
// MultiHeadedAttention forward, bf16 MFMA implementation. Round 2.
// B=4, T=2048, DIN=DOUT=1024, H=16, HD=64. Causal softmax, eval (no dropout).
// ---------------------------------------------------------------------------

typedef __bf16 bf16_t;
typedef __bf16 bf16x8 __attribute__((ext_vector_type(8)));
typedef float f32x4 __attribute__((ext_vector_type(4)));

#define BB 4
#define TT 2048
#define DK 1024
#define NH 16
#define HD 64

static __device__ __forceinline__ f32x4 mfma16(bf16x8 a, bf16x8 b, f32x4 c) {
  return __builtin_amdgcn_mfma_f32_16x16x32_bf16(a, b, c, 0, 0, 0);
}

// async global->LDS, 16B per lane; LDS dest must be wave-uniform base.
typedef __attribute__((address_space(1))) const unsigned int as1_uint;
typedef __attribute__((address_space(3))) unsigned int as3_uint;
static __device__ __forceinline__ void gload_lds16(const bf16_t* g, bf16_t* l) {
  __builtin_amdgcn_global_load_lds((as1_uint*)g, (as3_uint*)l, 16, 0, 0);
}

// ---- cast x (fp32) -> bf16, 8 elems/thread ---------------------------------
__global__ __launch_bounds__(256) void cast_x_kernel(const float* __restrict__ in,
                                                     bf16_t* __restrict__ out, int n8) {
  int i = blockIdx.x * blockDim.x + threadIdx.x;
  if (i < n8) {
    const float4* p = (const float4*)(in + (size_t)i * 8);
    float4 u = p[0], v = p[1];
    bf16x8 o = {(__bf16)u.x, (__bf16)u.y, (__bf16)u.z, (__bf16)u.w,
                (__bf16)v.x, (__bf16)v.y, (__bf16)v.z, (__bf16)v.w};
    *(bf16x8*)(out + (size_t)i * 8) = o;
  }
}

// ---- transpose + cast: W[K][N] fp32 -> Wt[N][K] bf16 (K=N=1024) ------------
__global__ __launch_bounds__(256) void transpose_cast_kernel(const float* __restrict__ W,
                                                             bf16_t* __restrict__ Wt) {
  __shared__ float tile[32][33];
  int bx = blockIdx.x * 32;
  int by = blockIdx.y * 32;
  int tx = threadIdx.x, ty = threadIdx.y;  // 32 x 8
#pragma unroll
  for (int i = 0; i < 32; i += 8)
    tile[ty + i][tx] = W[(size_t)(by + ty + i) * DK + bx + tx];
  __syncthreads();
#pragma unroll
  for (int i = 0; i < 32; i += 8)
    Wt[(size_t)(bx + ty + i) * DK + by + tx] = (bf16_t)tile[tx][ty + i];
}

// ---- GEMM (m97 structure): C[M][N] = A[M][K] * Bt[N][K]^T ------------------
// 128x128 tile, BK=32, 256 threads = 4 waves (2x2), each wave 64x64 (4x4 frags).
// Staging via global_load_lds width=16 into linear LDS [128][32] bf16.
// MODE 0: bf16 at [b,h,t,d] (Q,K);  MODE 1: bf16 at [b,h,d,t] (V^T);
// MODE 2: fp32 + bias at [row][col].
template <int MODE>
__global__ __launch_bounds__(256) void gemm_bt(const bf16_t* __restrict__ A,
                                               const bf16_t* __restrict__ Bt,
                                               void* __restrict__ Cout,
                                               const float* __restrict__ bias,
                                               int M, int N, int K) {
  __shared__ __align__(16) bf16_t As[128 * 32];
  __shared__ __align__(16) bf16_t Bs[128 * 32];
  const int tid = threadIdx.x;
  const int w = tid >> 6, lane = tid & 63, g = lane >> 4, r16 = lane & 15;
  const int m0 = blockIdx.y * 128, n0 = blockIdx.x * 128;
  const int wr = (w >> 1) * 64, wc = (w & 1) * 64;

  // staging: wave w covers rows [w*32, w*32+32) in two 16-row instructions.
  const int srow = w * 32 + (lane >> 2);       // + jj*16
  const int scol = (lane & 3) * 8;
  const bf16_t* Asrc = A + (size_t)(m0 + srow) * K + scol;
  const bf16_t* Bsrc = Bt + (size_t)(n0 + srow) * K + scol;
  bf16_t* AsW = &As[(w * 32) * 32];  // wave-uniform LDS base (row*32 elems)
  bf16_t* BsW = &Bs[(w * 32) * 32];

  f32x4 acc[4][4] = {};

  for (int k0 = 0; k0 < K; k0 += 32) {
    __syncthreads();
    gload_lds16(Asrc + k0, AsW);
    gload_lds16(Asrc + k0 + (size_t)16 * K, AsW + 16 * 32);
    gload_lds16(Bsrc + k0, BsW);
    gload_lds16(Bsrc + k0 + (size_t)16 * K, BsW + 16 * 32);
    __syncthreads();  // compiler drains vmcnt before the barrier -> tile ready

    bf16x8 a[4], b[4];
#pragma unroll
    for (int m = 0; m < 4; m++) a[m] = *(bf16x8*)&As[(wr + m * 16 + r16) * 32 + g * 8];
#pragma unroll
    for (int n = 0; n < 4; n++) b[n] = *(bf16x8*)&Bs[(wc + n * 16 + r16) * 32 + g * 8];
#pragma unroll
    for (int m = 0; m < 4; m++)
#pragma unroll
      for (int n = 0; n < 4; n++) acc[m][n] = mfma16(a[m], b[n], acc[m][n]);
  }

#pragma unroll
  for (int m = 0; m < 4; m++)
#pragma unroll
    for (int n = 0; n < 4; n++)
#pragma unroll
      for (int j = 0; j < 4; j++) {
        int row = m0 + wr + m * 16 + g * 4 + j;
        int col = n0 + wc + n * 16 + r16;
        float v = acc[m][n][j];
        if (MODE == 0) {
          int b_ = row >> 11, t = row & (TT - 1), h = col >> 6, d = col & 63;
          ((bf16_t*)Cout)[(((size_t)(b_ * NH + h) * TT + t) << 6) + d] = (bf16_t)v;
        } else if (MODE == 1) {
          int b_ = row >> 11, t = row & (TT - 1), h = col >> 6, d = col & 63;
          ((bf16_t*)Cout)[((size_t)(b_ * NH + h) * HD + d) * TT + t] = (bf16_t)v;
        } else {
          ((float*)Cout)[(size_t)row * N + col] = v + bias[col];
        }
      }
}

// ---- causal flash attention v2 ---------------------------------------------
// 256 threads = 4 waves; block = 128 q rows (32 per wave); KV tile = 64 keys.
// K tile [64k][64d] and V^T tile [64d][64k] staged in LDS, double-buffered,
// XOR-swizzled (chunk ^= row&7) via pre-swizzled global_load_lds source.
// Q,K: [b,h,t,64] bf16.  Vt: [b,h,64,t] bf16.  ctx out: [b,t,h*64+d] bf16.
__global__ __launch_bounds__(256) void attn_fwd(const bf16_t* __restrict__ Q,
                                                const bf16_t* __restrict__ K,
                                                const bf16_t* __restrict__ Vt,
                                                bf16_t* __restrict__ ctx) {
  __shared__ __align__(16) bf16_t Ks[2][64 * 64];
  __shared__ __align__(16) bf16_t Vs[2][64 * 64];
  __shared__ __align__(16) bf16_t Ps[4][32][72];  // per-wave P, padded rows

  const int tid = threadIdx.x;
  const int w = tid >> 6, lane = tid & 63, g = lane >> 4, r16 = lane & 15;
  const int qt = (gridDim.x - 1) - blockIdx.x;  // heavy blocks dispatch first
  const int bh = blockIdx.y;
  const int q0 = qt * 128, qw0 = q0 + w * 32;

  const bf16_t* Qp = Q + (size_t)bh * TT * HD;
  const bf16_t* Kp = K + (size_t)bh * TT * HD;
  const bf16_t* Vp = Vt + (size_t)bh * HD * TT;

  // Q fragments in registers: rows qw0 + m*16 + r16, k cols h*32 + g*8
  bf16x8 qf[2][2];
#pragma unroll
  for (int m = 0; m < 2; m++)
#pragma unroll
    for (int h = 0; h < 2; h++)
      qf[m][h] = *(const bf16x8*)&Qp[(size_t)(qw0 + m * 16 + r16) * HD + h * 32 + g * 8];

  float mrun[2][4], lrun[2][4];
  f32x4 o[2][4] = {};
#pragma unroll
  for (int m = 0; m < 2; m++)
#pragma unroll
    for (int j = 0; j < 4; j++) { mrun[m][j] = -1e30f; lrun[m][j] = 0.f; }

  // staging geometry: per wave 2 instructions x (K,V); lane i -> row w*16+j*8+(i>>3),
  // source chunk pre-swizzled so LDS[r][c] holds global chunk c ^ (r&7).
  const int sr_lo = (lane >> 3);      // 0..7 within 8-row slab
  const int sc = lane & 7;            // chunk 0..7
  auto stage = [&](int kt, int buf) {
    const int k0s = kt * 64;
#pragma unroll
    for (int j = 0; j < 2; j++) {
      int r = w * 16 + j * 8 + sr_lo;
      int cs = ((sc ^ (r & 7)) << 3);  // element offset of swizzled chunk
      gload_lds16(Kp + (size_t)(k0s + r) * HD + cs, &Ks[buf][(w * 16 + j * 8) * 64]);
      gload_lds16(Vp + (size_t)r * TT + k0s + cs, &Vs[buf][(w * 16 + j * 8) * 64]);
    }
  };

  const int nkt = 2 * (qt + 1);       // 64-key tiles covering k <= q0+127
  const int wmax = qw0 + 31;          // this wave's last q row

  stage(0, 0);
  __syncthreads();

  for (int kt = 0; kt < nkt; kt++) {
    const int cur = kt & 1;
    if (kt + 1 < nkt) stage(kt + 1, cur ^ 1);
    const int k0 = kt * 64;

    if (k0 <= wmax) {  // wave-uniform causal skip
      // ---- S = Q K^T over 64 keys (4 groups of 16) ----
      f32x4 s[2][4];
#pragma unroll
      for (int n = 0; n < 4; n++) {
        int kr = n * 16 + r16;
        bf16x8 kb0 = *(bf16x8*)&Ks[cur][kr * 64 + ((g ^ (kr & 7)) << 3)];
        bf16x8 kb1 = *(bf16x8*)&Ks[cur][kr * 64 + (((4 + g) ^ (kr & 7)) << 3)];
#pragma unroll
        for (int m = 0; m < 2; m++) {
          f32x4 z = {0.f, 0.f, 0.f, 0.f};
          s[m][n] = mfma16(qf[m][1], kb1, mfma16(qf[m][0], kb0, z));
        }
      }
      // ---- scale + causal mask ----
      float p[2][4][4];
#pragma unroll
      for (int m = 0; m < 2; m++)
#pragma unroll
        for (int n = 0; n < 4; n++)
#pragma unroll
          for (int j = 0; j < 4; j++) {
            float v = s[m][n][j] * 0.125f;
            int qg = qw0 + m * 16 + g * 4 + j, kg = k0 + n * 16 + r16;
            p[m][n][j] = (kg <= qg) ? v : -1e30f;
          }
      // ---- online softmax (row = (g,j) pair; reduce across r16 lanes) ----
#pragma unroll
      for (int m = 0; m < 2; m++)
#pragma unroll
        for (int j = 0; j < 4; j++) {
          float t = fmaxf(fmaxf(p[m][0][j], p[m][1][j]), fmaxf(p[m][2][j], p[m][3][j]));
          t = fmaxf(t, __shfl_xor(t, 1));
          t = fmaxf(t, __shfl_xor(t, 2));
          t = fmaxf(t, __shfl_xor(t, 4));
          t = fmaxf(t, __shfl_xor(t, 8));
          float mn = fmaxf(mrun[m][j], t);
          float fac = __expf(mrun[m][j] - mn);
          float rs = 0.f;
#pragma unroll
          for (int n = 0; n < 4; n++) {
            p[m][n][j] = __expf(p[m][n][j] - mn);
            rs += p[m][n][j];
          }
          rs += __shfl_xor(rs, 1);
          rs += __shfl_xor(rs, 2);
          rs += __shfl_xor(rs, 4);
          rs += __shfl_xor(rs, 8);
          lrun[m][j] = lrun[m][j] * fac + rs;
          mrun[m][j] = mn;
#pragma unroll
          for (int c = 0; c < 4; c++) o[m][c][j] *= fac;
        }
      // ---- P (C-layout) -> per-wave LDS -> A-fragment layout ----
#pragma unroll
      for (int m = 0; m < 2; m++)
#pragma unroll
        for (int n = 0; n < 4; n++)
#pragma unroll
          for (int j = 0; j < 4; j++)
            Ps[w][m * 16 + g * 4 + j][n * 16 + r16] = (bf16_t)p[m][n][j];
      asm volatile("s_waitcnt lgkmcnt(0)" ::: "memory");
      bf16x8 pa[2][2];
#pragma unroll
      for (int m = 0; m < 2; m++)
#pragma unroll
        for (int h2 = 0; h2 < 2; h2++)
          pa[m][h2] = *(bf16x8*)&Ps[w][m * 16 + r16][h2 * 32 + g * 8];
      // ---- O += P V ----
#pragma unroll
      for (int c = 0; c < 4; c++) {
        int vr = c * 16 + r16;
#pragma unroll
        for (int h2 = 0; h2 < 2; h2++) {
          bf16x8 vb = *(bf16x8*)&Vs[cur][vr * 64 + (((4 * h2 + g) ^ (vr & 7)) << 3)];
          o[0][c] = mfma16(pa[0][h2], vb, o[0][c]);
          o[1][c] = mfma16(pa[1][h2], vb, o[1][c]);
        }
      }
    }
    __syncthreads();  // next buffer staged + all waves done with cur
  }

  const int b = bh >> 4, h = bh & (NH - 1);
#pragma unroll
  for (int m = 0; m < 2; m++)
#pragma unroll
    for (int c = 0; c < 4; c++)
#pragma unroll
      for (int j = 0; j < 4; j++) {
        int q = qw0 + m * 16 + g * 4 + j, d = c * 16 + r16;
        float val = o[m][c][j] / lrun[m][j];
        ctx[((size_t)(b * TT + q)) * DK + h * HD + d] = (bf16_t)val;
      }
}

// ---------------------------------------------------------------------------
extern "C" void kernel_launch(void* const* d_in, const int* in_sizes, int n_in,
                              void* d_out, int out_size, void* d_ws, size_t ws_size,
                              hipStream_t stream) {
  const float* x = (const float*)d_in[0];
  const float* Wq = (const float*)d_in[1];
  const float* Wk = (const float*)d_in[2];
  const float* Wv = (const float*)d_in[3];
  const float* Wo = (const float*)d_in[4];
  const float* bo = (const float*)d_in[5];
  float* out = (float*)d_out;

  char* ws = (char*)d_ws;
  const size_t MB = 1u << 20;
  bf16_t* xb  = (bf16_t*)(ws + 0 * MB);
  bf16_t* Wqt = (bf16_t*)(ws + 16 * MB);
  bf16_t* Wkt = (bf16_t*)(ws + 18 * MB);
  bf16_t* Wvt = (bf16_t*)(ws + 20 * MB);
  bf16_t* Wot = (bf16_t*)(ws + 22 * MB);
  bf16_t* Qb  = (bf16_t*)(ws + 24 * MB);
  bf16_t* Kb  = (bf16_t*)(ws + 40 * MB);
  bf16_t* Vtb = (bf16_t*)(ws + 56 * MB);
  bf16_t* ctx = (bf16_t*)(ws + 72 * MB);

  const int M = BB * TT;  // 8192

  cast_x_kernel<<<(M * DK / 8 + 255) / 256, 256, 0, stream>>>(x, xb, M * DK / 8);

  dim3 tb(32, 8), tg(32, 32);
  transpose_cast_kernel<<<tg, tb, 0, stream>>>(Wq, Wqt);
  transpose_cast_kernel<<<tg, tb, 0, stream>>>(Wk, Wkt);
  transpose_cast_kernel<<<tg, tb, 0, stream>>>(Wv, Wvt);
  transpose_cast_kernel<<<tg, tb, 0, stream>>>(Wo, Wot);

  dim3 gg(DK / 128, M / 128);  // (8, 64)
  gemm_bt<0><<<gg, 256, 0, stream>>>(xb, Wqt, Qb, nullptr, M, DK, DK);
  gemm_bt<0><<<gg, 256, 0, stream>>>(xb, Wkt, Kb, nullptr, M, DK, DK);
  gemm_bt<1><<<gg, 256, 0, stream>>>(xb, Wvt, Vtb, nullptr, M, DK, DK);

  attn_fwd<<<dim3(TT / 128, BB * NH), 256, 0, stream>>>(Qb, Kb, Vtb, ctx);

  gemm_bt<2><<<gg, 256, 0, stream>>>(ctx, Wot, out, bo, M, DK, DK);
}

// Round 5
// 313.612 us; speedup vs baseline: 1.8695x; 1.4560x over previous
//
#include <hip/hip_runtime.h>

// ---------------------------------------------------------------------------
// MultiHeadedAttention forward, bf16 MFMA implementation. Round 5.
// B=4, T=2048, DIN=DOUT=1024, H=16, HD=64. Causal softmax, eval (no dropout).
// ---------------------------------------------------------------------------

typedef __bf16 bf16_t;
typedef __bf16 bf16x4 __attribute__((ext_vector_type(4)));
typedef __bf16 bf16x8 __attribute__((ext_vector_type(8)));
typedef float f32x4 __attribute__((ext_vector_type(4)));

#define BB 4
#define TT 2048
#define DK 1024
#define NH 16
#define HD 64

static __device__ __forceinline__ f32x4 mfma16(bf16x8 a, bf16x8 b, f32x4 c) {
  return __builtin_amdgcn_mfma_f32_16x16x32_bf16(a, b, c, 0, 0, 0);
}

// 2^x via v_exp_f32 directly (avoids glibc __exp2f macro collision).
static __device__ __forceinline__ float exp2_hw(float x) {
  return __builtin_amdgcn_exp2f(x);
}

typedef __attribute__((address_space(1))) const unsigned int as1_uint;
typedef __attribute__((address_space(3))) unsigned int as3_uint;
static __device__ __forceinline__ void gload_lds16(const bf16_t* g, bf16_t* l) {
  __builtin_amdgcn_global_load_lds((as1_uint*)g, (as3_uint*)l, 16, 0, 0);
}

// ---- cast x (fp32) -> bf16, 8 elems/thread ---------------------------------
__global__ __launch_bounds__(256) void cast_x_kernel(const float* __restrict__ in,
                                                     bf16_t* __restrict__ out, int n8) {
  int i = blockIdx.x * blockDim.x + threadIdx.x;
  if (i < n8) {
    const float4* p = (const float4*)(in + (size_t)i * 8);
    float4 u = p[0], v = p[1];
    bf16x8 o = {(__bf16)u.x, (__bf16)u.y, (__bf16)u.z, (__bf16)u.w,
                (__bf16)v.x, (__bf16)v.y, (__bf16)v.z, (__bf16)v.w};
    *(bf16x8*)(out + (size_t)i * 8) = o;
  }
}

// ---- transpose + cast: W[K][N] fp32 -> Wt[N][K] bf16 (K=N=1024) ------------
__global__ __launch_bounds__(256) void transpose_cast_kernel(const float* __restrict__ W,
                                                             bf16_t* __restrict__ Wt) {
  __shared__ float tile[32][33];
  int bx = blockIdx.x * 32;
  int by = blockIdx.y * 32;
  int tx = threadIdx.x, ty = threadIdx.y;  // 32 x 8
#pragma unroll
  for (int i = 0; i < 32; i += 8)
    tile[ty + i][tx] = W[(size_t)(by + ty + i) * DK + bx + tx];
  __syncthreads();
#pragma unroll
  for (int i = 0; i < 32; i += 8)
    Wt[(size_t)(bx + ty + i) * DK + by + tx] = (bf16_t)tile[tx][ty + i];
}

// ---- GEMM (m97 structure): C[M][N] = A[M][K] * Bt[N][K]^T ------------------
// 128x128 tile, BK=32, 256 threads = 4 waves (2x2), each wave 64x64 (4x4).
// MODE 0: fused QKV (N=3072): proj=n0>>10 -> Q/K: bf16 [b,h,t,d]; V: [b,h,d,t]
// MODE 2: fp32 + bias at [row][col]
template <int MODE>
__global__ __launch_bounds__(256) void gemm_bt(const bf16_t* __restrict__ A,
                                               const bf16_t* __restrict__ Bt,
                                               void* __restrict__ out0,
                                               void* __restrict__ out1,
                                               void* __restrict__ out2,
                                               const float* __restrict__ bias,
                                               int M, int N, int K) {
  __shared__ __align__(16) bf16_t As[128 * 32];
  __shared__ __align__(16) bf16_t Bs[128 * 32];
  const int tid = threadIdx.x;
  const int w = tid >> 6, lane = tid & 63, g = lane >> 4, r16 = lane & 15;
  const int m0 = blockIdx.y * 128, n0 = blockIdx.x * 128;
  const int wr = (w >> 1) * 64, wc = (w & 1) * 64;

  const int srow = w * 32 + (lane >> 2);
  const int scol = (lane & 3) * 8;
  const bf16_t* Asrc = A + (size_t)(m0 + srow) * K + scol;
  const bf16_t* Bsrc = Bt + (size_t)(n0 + srow) * K + scol;
  bf16_t* AsW = &As[(w * 32) * 32];
  bf16_t* BsW = &Bs[(w * 32) * 32];

  f32x4 acc[4][4] = {};

  for (int k0 = 0; k0 < K; k0 += 32) {
    __syncthreads();
    gload_lds16(Asrc + k0, AsW);
    gload_lds16(Asrc + k0 + (size_t)16 * K, AsW + 16 * 32);
    gload_lds16(Bsrc + k0, BsW);
    gload_lds16(Bsrc + k0 + (size_t)16 * K, BsW + 16 * 32);
    __syncthreads();

    bf16x8 a[4], b[4];
#pragma unroll
    for (int m = 0; m < 4; m++) a[m] = *(bf16x8*)&As[(wr + m * 16 + r16) * 32 + g * 8];
#pragma unroll
    for (int n = 0; n < 4; n++) b[n] = *(bf16x8*)&Bs[(wc + n * 16 + r16) * 32 + g * 8];
#pragma unroll
    for (int m = 0; m < 4; m++)
#pragma unroll
      for (int n = 0; n < 4; n++) acc[m][n] = mfma16(a[m], b[n], acc[m][n]);
  }

  const int proj = n0 >> 10;  // MODE 0: which of Q/K/V (tiles never straddle)
#pragma unroll
  for (int m = 0; m < 4; m++)
#pragma unroll
    for (int n = 0; n < 4; n++)
#pragma unroll
      for (int j = 0; j < 4; j++) {
        int row = m0 + wr + m * 16 + g * 4 + j;
        int colg = n0 + wc + n * 16 + r16;
        float v = acc[m][n][j];
        if (MODE == 0) {
          int col = colg & (DK - 1);
          int b_ = row >> 11, t = row & (TT - 1), h = col >> 6, d = col & 63;
          if (proj == 0)
            ((bf16_t*)out0)[(((size_t)(b_ * NH + h) * TT + t) << 6) + d] = (bf16_t)v;
          else if (proj == 1)
            ((bf16_t*)out1)[(((size_t)(b_ * NH + h) * TT + t) << 6) + d] = (bf16_t)v;
          else
            ((bf16_t*)out2)[((size_t)(b_ * NH + h) * HD + d) * TT + t] = (bf16_t)v;
        } else {
          ((float*)out0)[(size_t)row * N + colg] = v + bias[colg];
        }
      }
}

// ---- causal flash attention v3 ---------------------------------------------
// 256 threads = 4 waves; q-block = 128 rows (32/wave); KV tile = 64 keys.
// Pair-balanced grid: block x does q-tiles {x, 15-x} (34 key-tiles each).
// Swapped QK^T: S^T = mfma(K, Q) -> each lane owns 16 of the 64 keys for ONE
// q row; row reduce = local tree + shfl_xor(16,32). exp2-domain softmax.
__global__ __launch_bounds__(256) void attn_fwd(const bf16_t* __restrict__ Q,
                                                const bf16_t* __restrict__ K,
                                                const bf16_t* __restrict__ Vt,
                                                bf16_t* __restrict__ ctx) {
  __shared__ __align__(16) bf16_t Ks[2][64 * 64];
  __shared__ __align__(16) bf16_t Vs[2][64 * 64];
  __shared__ __align__(16) bf16_t Ps[4][32][72];

  const int tid = threadIdx.x;
  const int w = tid >> 6, lane = tid & 63, g = lane >> 4, r16 = lane & 15;
  const int bh = blockIdx.y;
  const int b = bh >> 4, h = bh & (NH - 1);

  const bf16_t* Qp = Q + (size_t)bh * TT * HD;
  const bf16_t* Kp = K + (size_t)bh * TT * HD;
  const bf16_t* Vp = Vt + (size_t)bh * HD * TT;

  const int sr_lo = (lane >> 3);
  const int sc = lane & 7;
  auto stage = [&](int kt, int buf) {
    const int k0s = kt * 64;
#pragma unroll
    for (int j = 0; j < 2; j++) {
      int r = w * 16 + j * 8 + sr_lo;
      int cs = ((sc ^ (r & 7)) << 3);
      gload_lds16(Kp + (size_t)(k0s + r) * HD + cs, &Ks[buf][(w * 16 + j * 8) * 64]);
      gload_lds16(Vp + (size_t)r * TT + k0s + cs, &Vs[buf][(w * 16 + j * 8) * 64]);
    }
  };

  const float SC = 0.18033688011112042f;  // 0.125 * log2(e)

  auto run_qtile = [&](int qt) {
    const int q0 = qt * 128, qw0 = q0 + w * 32;
    bf16x8 qf[2][2];
#pragma unroll
    for (int m = 0; m < 2; m++)
#pragma unroll
      for (int hh = 0; hh < 2; hh++)
        qf[m][hh] = *(const bf16x8*)&Qp[(size_t)(qw0 + m * 16 + r16) * HD + hh * 32 + g * 8];

    float mrun[2] = {-1e30f, -1e30f}, lrun[2] = {0.f, 0.f};
    f32x4 o[2][4] = {};

    const int nkt = 2 * (qt + 1);  // always even
    const int wmax = qw0 + 31;

    stage(0, 0);
    __syncthreads();

    for (int kt = 0; kt < nkt; kt++) {
      const int cur = kt & 1;
      if (kt + 1 < nkt) stage(kt + 1, cur ^ 1);
      const int k0 = kt * 64;

      if (k0 <= wmax) {
        // ---- S^T = K Q^T : lane owns q = qw0+mB*16+r16, k = k0+a*16+g*4+j --
        f32x4 sT[4][2];
#pragma unroll
        for (int a = 0; a < 4; a++) {
          int kr = a * 16 + r16;
          bf16x8 kb0 = *(bf16x8*)&Ks[cur][kr * 64 + ((g ^ (kr & 7)) << 3)];
          bf16x8 kb1 = *(bf16x8*)&Ks[cur][kr * 64 + (((4 + g) ^ (kr & 7)) << 3)];
#pragma unroll
          for (int mB = 0; mB < 2; mB++) {
            f32x4 z = {0.f, 0.f, 0.f, 0.f};
            sT[a][mB] = mfma16(kb1, qf[mB][1], mfma16(kb0, qf[mB][0], z));
          }
        }
        // ---- scale (+ mask on tiles that reach the diagonal) ----
        float p[2][4][4];
#pragma unroll
        for (int mB = 0; mB < 2; mB++)
#pragma unroll
          for (int a = 0; a < 4; a++)
#pragma unroll
            for (int j = 0; j < 4; j++) p[mB][a][j] = sT[a][mB][j] * SC;
        // Mask unless the whole tile is below the diagonal for EVERY row of
        // this wave: safe iff k0+63 <= qw0 (min q row). [R4 bug: used wmax]
        if (k0 + 63 > qw0) {
#pragma unroll
          for (int mB = 0; mB < 2; mB++) {
            int qq = qw0 + mB * 16 + r16;
#pragma unroll
            for (int a = 0; a < 4; a++)
#pragma unroll
              for (int j = 0; j < 4; j++) {
                int kq = k0 + a * 16 + g * 4 + j;
                if (kq > qq) p[mB][a][j] = -1e30f;
              }
          }
        }
        // ---- online softmax, exp2 domain; per-lane rows ----
        float fac[2];
#pragma unroll
        for (int mB = 0; mB < 2; mB++) {
          float ta[4], sa[4];
#pragma unroll
          for (int a = 0; a < 4; a++)
            ta[a] = fmaxf(fmaxf(p[mB][a][0], p[mB][a][1]),
                          fmaxf(p[mB][a][2], p[mB][a][3]));
          float t = fmaxf(fmaxf(ta[0], ta[1]), fmaxf(ta[2], ta[3]));
          t = fmaxf(t, __shfl_xor(t, 16));
          t = fmaxf(t, __shfl_xor(t, 32));
          float mn = fmaxf(mrun[mB], t);
          fac[mB] = exp2_hw(mrun[mB] - mn);
#pragma unroll
          for (int a = 0; a < 4; a++) {
#pragma unroll
            for (int j = 0; j < 4; j++) p[mB][a][j] = exp2_hw(p[mB][a][j] - mn);
            sa[a] = (p[mB][a][0] + p[mB][a][1]) + (p[mB][a][2] + p[mB][a][3]);
          }
          float rs = (sa[0] + sa[1]) + (sa[2] + sa[3]);
          rs += __shfl_xor(rs, 16);
          rs += __shfl_xor(rs, 32);
          lrun[mB] = lrun[mB] * fac[mB] + rs;
          mrun[mB] = mn;
        }
        // ---- P -> Ps (packed b64 writes) ----
#pragma unroll
        for (int mB = 0; mB < 2; mB++)
#pragma unroll
          for (int a = 0; a < 4; a++) {
            bf16x4 pk = {(__bf16)p[mB][a][0], (__bf16)p[mB][a][1],
                         (__bf16)p[mB][a][2], (__bf16)p[mB][a][3]};
            *(bf16x4*)&Ps[w][mB * 16 + r16][a * 16 + g * 4] = pk;
          }
        // ---- redistribute fac to O layout, rescale ----
        float f_[2][4];
#pragma unroll
        for (int j = 0; j < 4; j++) {
          f_[0][j] = __shfl(fac[0], g * 4 + j);
          f_[1][j] = __shfl(fac[1], g * 4 + j);
        }
#pragma unroll
        for (int m = 0; m < 2; m++)
#pragma unroll
          for (int c = 0; c < 4; c++)
#pragma unroll
            for (int j = 0; j < 4; j++) o[m][c][j] *= f_[m][j];
        asm volatile("s_waitcnt lgkmcnt(0)" ::: "memory");
        bf16x8 pa[2][2];
#pragma unroll
        for (int m = 0; m < 2; m++)
#pragma unroll
          for (int h2 = 0; h2 < 2; h2++)
            pa[m][h2] = *(bf16x8*)&Ps[w][m * 16 + r16][h2 * 32 + g * 8];
        // ---- O += P V ----
#pragma unroll
        for (int c = 0; c < 4; c++) {
          int vr = c * 16 + r16;
#pragma unroll
          for (int h2 = 0; h2 < 2; h2++) {
            bf16x8 vb = *(bf16x8*)&Vs[cur][vr * 64 + (((4 * h2 + g) ^ (vr & 7)) << 3)];
            o[0][c] = mfma16(pa[0][h2], vb, o[0][c]);
            o[1][c] = mfma16(pa[1][h2], vb, o[1][c]);
          }
        }
      }
      __syncthreads();
    }

    // ---- epilogue: divide by l (redistributed), store ----
    float linv[2];
#pragma unroll
    for (int mB = 0; mB < 2; mB++) linv[mB] = 1.0f / lrun[mB];
    float li[2][4];
#pragma unroll
    for (int j = 0; j < 4; j++) {
      li[0][j] = __shfl(linv[0], g * 4 + j);
      li[1][j] = __shfl(linv[1], g * 4 + j);
    }
#pragma unroll
    for (int m = 0; m < 2; m++)
#pragma unroll
      for (int c = 0; c < 4; c++)
#pragma unroll
        for (int j = 0; j < 4; j++) {
          int q = qw0 + m * 16 + g * 4 + j, d = c * 16 + r16;
          ctx[((size_t)(b * TT + q)) * DK + h * HD + d] = (bf16_t)(o[m][c][j] * li[m][j]);
        }
  };

  run_qtile(blockIdx.x);       // light tile (x in 0..7)
  run_qtile(15 - blockIdx.x);  // heavy tile -> constant total work per block
}

// ---------------------------------------------------------------------------
extern "C" void kernel_launch(void* const* d_in, const int* in_sizes, int n_in,
                              void* d_out, int out_size, void* d_ws, size_t ws_size,
                              hipStream_t stream) {
  const float* x = (const float*)d_in[0];
  const float* Wq = (const float*)d_in[1];
  const float* Wk = (const float*)d_in[2];
  const float* Wv = (const float*)d_in[3];
  const float* Wo = (const float*)d_in[4];
  const float* bo = (const float*)d_in[5];
  float* out = (float*)d_out;

  char* ws = (char*)d_ws;
  const size_t MB = 1u << 20;
  bf16_t* xb    = (bf16_t*)(ws + 0 * MB);    // 16 MB
  bf16_t* Wqkvt = (bf16_t*)(ws + 16 * MB);   // 6 MB: [3][1024][1024] N-major
  bf16_t* Wot   = (bf16_t*)(ws + 22 * MB);   // 2 MB
  bf16_t* Qb    = (bf16_t*)(ws + 24 * MB);   // 16 MB [b,h,t,d]
  bf16_t* Kb    = (bf16_t*)(ws + 40 * MB);   // 16 MB [b,h,t,d]
  bf16_t* Vtb   = (bf16_t*)(ws + 56 * MB);   // 16 MB [b,h,d,t]
  bf16_t* ctx   = (bf16_t*)(ws + 72 * MB);   // 16 MB [b,t,h*64+d]

  const int M = BB * TT;  // 8192

  cast_x_kernel<<<(M * DK / 8 + 255) / 256, 256, 0, stream>>>(x, xb, M * DK / 8);

  dim3 tb(32, 8), tg(32, 32);
  transpose_cast_kernel<<<tg, tb, 0, stream>>>(Wq, Wqkvt);
  transpose_cast_kernel<<<tg, tb, 0, stream>>>(Wk, Wqkvt + (size_t)DK * DK);
  transpose_cast_kernel<<<tg, tb, 0, stream>>>(Wv, Wqkvt + (size_t)2 * DK * DK);
  transpose_cast_kernel<<<tg, tb, 0, stream>>>(Wo, Wot);

  // fused QKV: 8192 x 3072 x 1024
  gemm_bt<0><<<dim3(3 * DK / 128, M / 128), 256, 0, stream>>>(
      xb, Wqkvt, Qb, Kb, Vtb, nullptr, M, 3 * DK, DK);

  attn_fwd<<<dim3(TT / 256, BB * NH), 256, 0, stream>>>(Qb, Kb, Vtb, ctx);

  gemm_bt<2><<<dim3(DK / 128, M / 128), 256, 0, stream>>>(
      ctx, Wot, out, nullptr, nullptr, bo, M, DK, DK);
}

// Round 6
// 275.874 us; speedup vs baseline: 2.1253x; 1.1368x over previous
//
#include <hip/hip_runtime.h>

// ---------------------------------------------------------------------------
// MultiHeadedAttention forward, bf16 MFMA implementation. Round 6.
// B=4, T=2048, DIN=DOUT=1024, H=16, HD=64. Causal softmax, eval (no dropout).
// ---------------------------------------------------------------------------

typedef __bf16 bf16_t;
typedef __bf16 bf16x4 __attribute__((ext_vector_type(4)));
typedef __bf16 bf16x8 __attribute__((ext_vector_type(8)));
typedef float f32x4 __attribute__((ext_vector_type(4)));

#define BB 4
#define TT 2048
#define DK 1024
#define NH 16
#define HD 64

static __device__ __forceinline__ f32x4 mfma16(bf16x8 a, bf16x8 b, f32x4 c) {
  return __builtin_amdgcn_mfma_f32_16x16x32_bf16(a, b, c, 0, 0, 0);
}

// 2^x via v_exp_f32 directly (avoids glibc __exp2f macro collision).
static __device__ __forceinline__ float exp2_hw(float x) {
  return __builtin_amdgcn_exp2f(x);
}

typedef __attribute__((address_space(1))) const unsigned int as1_uint;
typedef __attribute__((address_space(3))) unsigned int as3_uint;
static __device__ __forceinline__ void gload_lds16(const bf16_t* g, bf16_t* l) {
  __builtin_amdgcn_global_load_lds((as1_uint*)g, (as3_uint*)l, 16, 0, 0);
}

// ---- cast x (fp32) -> bf16, 8 elems/thread ---------------------------------
__global__ __launch_bounds__(256) void cast_x_kernel(const float* __restrict__ in,
                                                     bf16_t* __restrict__ out, int n8) {
  int i = blockIdx.x * blockDim.x + threadIdx.x;
  if (i < n8) {
    const float4* p = (const float4*)(in + (size_t)i * 8);
    float4 u = p[0], v = p[1];
    bf16x8 o = {(__bf16)u.x, (__bf16)u.y, (__bf16)u.z, (__bf16)u.w,
                (__bf16)v.x, (__bf16)v.y, (__bf16)v.z, (__bf16)v.w};
    *(bf16x8*)(out + (size_t)i * 8) = o;
  }
}

// ---- transpose + cast all 4 weights in one launch (z selects matrix) -------
__global__ __launch_bounds__(256) void transpose_cast4_kernel(
    const float* __restrict__ W0, const float* __restrict__ W1,
    const float* __restrict__ W2, const float* __restrict__ W3,
    bf16_t* __restrict__ dstQKV, bf16_t* __restrict__ dstO) {
  __shared__ float tile[32][33];
  const int z = blockIdx.z;
  const float* W = (z == 0) ? W0 : (z == 1) ? W1 : (z == 2) ? W2 : W3;
  bf16_t* Wt = (z < 3) ? dstQKV + (size_t)z * DK * DK : dstO;
  int bx = blockIdx.x * 32;
  int by = blockIdx.y * 32;
  int tx = threadIdx.x, ty = threadIdx.y;  // 32 x 8
#pragma unroll
  for (int i = 0; i < 32; i += 8)
    tile[ty + i][tx] = W[(size_t)(by + ty + i) * DK + bx + tx];
  __syncthreads();
#pragma unroll
  for (int i = 0; i < 32; i += 8)
    Wt[(size_t)(bx + ty + i) * DK + by + tx] = (bf16_t)tile[tx][ty + i];
}

// ---- GEMM, min-2-phase pipelined: C[M][N] = A[M][K] * Bt[N][K]^T -----------
// 128x128 tile, BK=32, 256 threads = 4 waves (2x2), each wave 64x64 (4x4).
// LDS double-buffered; stage(next) issued BEFORE compute(cur); one barrier/iter
// so global_load_lds overlaps ds_read+MFMA. setprio(1) around MFMA cluster.
// MODE 0: fused QKV (N=3072): proj=n0>>10 -> Q/K: bf16 [b,h,t,d]; V: [b,h,d,t]
// MODE 2: fp32 + bias at [row][col]
template <int MODE>
__global__ __launch_bounds__(256) void gemm_bt(const bf16_t* __restrict__ A,
                                               const bf16_t* __restrict__ Bt,
                                               void* __restrict__ out0,
                                               void* __restrict__ out1,
                                               void* __restrict__ out2,
                                               const float* __restrict__ bias,
                                               int M, int N, int K) {
  __shared__ __align__(16) bf16_t As[2][128 * 32];
  __shared__ __align__(16) bf16_t Bs[2][128 * 32];
  const int tid = threadIdx.x;
  const int w = tid >> 6, lane = tid & 63, g = lane >> 4, r16 = lane & 15;
  const int m0 = blockIdx.y * 128, n0 = blockIdx.x * 128;
  const int wr = (w >> 1) * 64, wc = (w & 1) * 64;

  const int srow = w * 32 + (lane >> 2);
  const int scol = (lane & 3) * 8;
  const bf16_t* Asrc = A + (size_t)(m0 + srow) * K + scol;
  const bf16_t* Bsrc = Bt + (size_t)(n0 + srow) * K + scol;

  auto stage = [&](int k0, int buf) {
    gload_lds16(Asrc + k0, &As[buf][(w * 32) * 32]);
    gload_lds16(Asrc + k0 + (size_t)16 * K, &As[buf][(w * 32 + 16) * 32]);
    gload_lds16(Bsrc + k0, &Bs[buf][(w * 32) * 32]);
    gload_lds16(Bsrc + k0 + (size_t)16 * K, &Bs[buf][(w * 32 + 16) * 32]);
  };

  f32x4 acc[4][4] = {};

  stage(0, 0);
  asm volatile("s_waitcnt vmcnt(0)" ::: "memory");
  __syncthreads();

  int cur = 0;
  for (int k0 = 0; k0 < K; k0 += 32) {
    if (k0 + 32 < K) stage(k0 + 32, cur ^ 1);  // issue loads early: overlap

    bf16x8 a[4], b[4];
#pragma unroll
    for (int m = 0; m < 4; m++)
      a[m] = *(bf16x8*)&As[cur][(wr + m * 16 + r16) * 32 + g * 8];
#pragma unroll
    for (int n = 0; n < 4; n++)
      b[n] = *(bf16x8*)&Bs[cur][(wc + n * 16 + r16) * 32 + g * 8];

    __builtin_amdgcn_s_setprio(1);
#pragma unroll
    for (int m = 0; m < 4; m++)
#pragma unroll
      for (int n = 0; n < 4; n++) acc[m][n] = mfma16(a[m], b[n], acc[m][n]);
    __builtin_amdgcn_s_setprio(0);

    asm volatile("s_waitcnt vmcnt(0)" ::: "memory");
    __syncthreads();
    cur ^= 1;
  }

  const int proj = n0 >> 10;  // MODE 0: which of Q/K/V (tiles never straddle)
  if (MODE == 0 && proj == 2) {
    // V^T: the 4 j-values are t-contiguous -> one 8B store per fragment.
#pragma unroll
    for (int m = 0; m < 4; m++)
#pragma unroll
      for (int n = 0; n < 4; n++) {
        int row0 = m0 + wr + m * 16 + g * 4;
        int col = (n0 + wc + n * 16 + r16) & (DK - 1);
        int b_ = row0 >> 11, t0 = row0 & (TT - 1), h = col >> 6, d = col & 63;
        bf16x4 pk = {(bf16_t)acc[m][n][0], (bf16_t)acc[m][n][1],
                     (bf16_t)acc[m][n][2], (bf16_t)acc[m][n][3]};
        *(bf16x4*)&((bf16_t*)out2)[((size_t)(b_ * NH + h) * HD + d) * TT + t0] = pk;
      }
  } else {
#pragma unroll
    for (int m = 0; m < 4; m++)
#pragma unroll
      for (int n = 0; n < 4; n++)
#pragma unroll
        for (int j = 0; j < 4; j++) {
          int row = m0 + wr + m * 16 + g * 4 + j;
          int colg = n0 + wc + n * 16 + r16;
          float v = acc[m][n][j];
          if (MODE == 0) {
            int col = colg & (DK - 1);
            int b_ = row >> 11, t = row & (TT - 1), h = col >> 6, d = col & 63;
            if (proj == 0)
              ((bf16_t*)out0)[(((size_t)(b_ * NH + h) * TT + t) << 6) + d] = (bf16_t)v;
            else
              ((bf16_t*)out1)[(((size_t)(b_ * NH + h) * TT + t) << 6) + d] = (bf16_t)v;
          } else {
            ((float*)out0)[(size_t)row * N + colg] = v + bias[colg];
          }
        }
  }
}

// ---- causal flash attention v3 ---------------------------------------------
// 256 threads = 4 waves; q-block = 128 rows (32/wave); KV tile = 64 keys.
// Pair-balanced grid: block x does q-tiles {x, 15-x} (34 key-tiles each).
// Swapped QK^T: S^T = mfma(K, Q) -> each lane owns 16 of the 64 keys for ONE
// q row; row reduce = local tree + shfl_xor(16,32). exp2-domain softmax.
__global__ __launch_bounds__(256) void attn_fwd(const bf16_t* __restrict__ Q,
                                                const bf16_t* __restrict__ K,
                                                const bf16_t* __restrict__ Vt,
                                                bf16_t* __restrict__ ctx) {
  __shared__ __align__(16) bf16_t Ks[2][64 * 64];
  __shared__ __align__(16) bf16_t Vs[2][64 * 64];
  __shared__ __align__(16) bf16_t Ps[4][32][72];

  const int tid = threadIdx.x;
  const int w = tid >> 6, lane = tid & 63, g = lane >> 4, r16 = lane & 15;
  const int bh = blockIdx.y;
  const int b = bh >> 4, h = bh & (NH - 1);

  const bf16_t* Qp = Q + (size_t)bh * TT * HD;
  const bf16_t* Kp = K + (size_t)bh * TT * HD;
  const bf16_t* Vp = Vt + (size_t)bh * HD * TT;

  const int sr_lo = (lane >> 3);
  const int sc = lane & 7;
  auto stage = [&](int kt, int buf) {
    const int k0s = kt * 64;
#pragma unroll
    for (int j = 0; j < 2; j++) {
      int r = w * 16 + j * 8 + sr_lo;
      int cs = ((sc ^ (r & 7)) << 3);
      gload_lds16(Kp + (size_t)(k0s + r) * HD + cs, &Ks[buf][(w * 16 + j * 8) * 64]);
      gload_lds16(Vp + (size_t)r * TT + k0s + cs, &Vs[buf][(w * 16 + j * 8) * 64]);
    }
  };

  const float SC = 0.18033688011112042f;  // 0.125 * log2(e)

  auto run_qtile = [&](int qt) {
    const int q0 = qt * 128, qw0 = q0 + w * 32;
    bf16x8 qf[2][2];
#pragma unroll
    for (int m = 0; m < 2; m++)
#pragma unroll
      for (int hh = 0; hh < 2; hh++)
        qf[m][hh] = *(const bf16x8*)&Qp[(size_t)(qw0 + m * 16 + r16) * HD + hh * 32 + g * 8];

    float mrun[2] = {-1e30f, -1e30f}, lrun[2] = {0.f, 0.f};
    f32x4 o[2][4] = {};

    const int nkt = 2 * (qt + 1);  // always even
    const int wmax = qw0 + 31;

    stage(0, 0);
    __syncthreads();

    for (int kt = 0; kt < nkt; kt++) {
      const int cur = kt & 1;
      if (kt + 1 < nkt) stage(kt + 1, cur ^ 1);
      const int k0 = kt * 64;

      if (k0 <= wmax) {
        // ---- S^T = K Q^T : lane owns q = qw0+mB*16+r16, k = k0+a*16+g*4+j --
        f32x4 sT[4][2];
        __builtin_amdgcn_s_setprio(1);
#pragma unroll
        for (int a = 0; a < 4; a++) {
          int kr = a * 16 + r16;
          bf16x8 kb0 = *(bf16x8*)&Ks[cur][kr * 64 + ((g ^ (kr & 7)) << 3)];
          bf16x8 kb1 = *(bf16x8*)&Ks[cur][kr * 64 + (((4 + g) ^ (kr & 7)) << 3)];
#pragma unroll
          for (int mB = 0; mB < 2; mB++) {
            f32x4 z = {0.f, 0.f, 0.f, 0.f};
            sT[a][mB] = mfma16(kb1, qf[mB][1], mfma16(kb0, qf[mB][0], z));
          }
        }
        __builtin_amdgcn_s_setprio(0);
        // ---- scale (+ mask on tiles that reach the diagonal) ----
        float p[2][4][4];
#pragma unroll
        for (int mB = 0; mB < 2; mB++)
#pragma unroll
          for (int a = 0; a < 4; a++)
#pragma unroll
            for (int j = 0; j < 4; j++) p[mB][a][j] = sT[a][mB][j] * SC;
        // Mask unless the whole tile is below the diagonal for EVERY row of
        // this wave: safe iff k0+63 <= qw0 (min q row).
        if (k0 + 63 > qw0) {
#pragma unroll
          for (int mB = 0; mB < 2; mB++) {
            int qq = qw0 + mB * 16 + r16;
#pragma unroll
            for (int a = 0; a < 4; a++)
#pragma unroll
              for (int j = 0; j < 4; j++) {
                int kq = k0 + a * 16 + g * 4 + j;
                if (kq > qq) p[mB][a][j] = -1e30f;
              }
          }
        }
        // ---- online softmax, exp2 domain; per-lane rows ----
        float fac[2];
#pragma unroll
        for (int mB = 0; mB < 2; mB++) {
          float ta[4], sa[4];
#pragma unroll
          for (int a = 0; a < 4; a++)
            ta[a] = fmaxf(fmaxf(p[mB][a][0], p[mB][a][1]),
                          fmaxf(p[mB][a][2], p[mB][a][3]));
          float t = fmaxf(fmaxf(ta[0], ta[1]), fmaxf(ta[2], ta[3]));
          t = fmaxf(t, __shfl_xor(t, 16));
          t = fmaxf(t, __shfl_xor(t, 32));
          float mn = fmaxf(mrun[mB], t);
          fac[mB] = exp2_hw(mrun[mB] - mn);
#pragma unroll
          for (int a = 0; a < 4; a++) {
#pragma unroll
            for (int j = 0; j < 4; j++) p[mB][a][j] = exp2_hw(p[mB][a][j] - mn);
            sa[a] = (p[mB][a][0] + p[mB][a][1]) + (p[mB][a][2] + p[mB][a][3]);
          }
          float rs = (sa[0] + sa[1]) + (sa[2] + sa[3]);
          rs += __shfl_xor(rs, 16);
          rs += __shfl_xor(rs, 32);
          lrun[mB] = lrun[mB] * fac[mB] + rs;
          mrun[mB] = mn;
        }
        // ---- P -> Ps (packed b64 writes) ----
#pragma unroll
        for (int mB = 0; mB < 2; mB++)
#pragma unroll
          for (int a = 0; a < 4; a++) {
            bf16x4 pk = {(__bf16)p[mB][a][0], (__bf16)p[mB][a][1],
                         (__bf16)p[mB][a][2], (__bf16)p[mB][a][3]};
            *(bf16x4*)&Ps[w][mB * 16 + r16][a * 16 + g * 4] = pk;
          }
        // ---- redistribute fac to O layout, rescale ----
        float f_[2][4];
#pragma unroll
        for (int j = 0; j < 4; j++) {
          f_[0][j] = __shfl(fac[0], g * 4 + j);
          f_[1][j] = __shfl(fac[1], g * 4 + j);
        }
#pragma unroll
        for (int m = 0; m < 2; m++)
#pragma unroll
          for (int c = 0; c < 4; c++)
#pragma unroll
            for (int j = 0; j < 4; j++) o[m][c][j] *= f_[m][j];
        asm volatile("s_waitcnt lgkmcnt(0)" ::: "memory");
        bf16x8 pa[2][2];
#pragma unroll
        for (int m = 0; m < 2; m++)
#pragma unroll
          for (int h2 = 0; h2 < 2; h2++)
            pa[m][h2] = *(bf16x8*)&Ps[w][m * 16 + r16][h2 * 32 + g * 8];
        // ---- O += P V ----
        __builtin_amdgcn_s_setprio(1);
#pragma unroll
        for (int c = 0; c < 4; c++) {
          int vr = c * 16 + r16;
#pragma unroll
          for (int h2 = 0; h2 < 2; h2++) {
            bf16x8 vb = *(bf16x8*)&Vs[cur][vr * 64 + (((4 * h2 + g) ^ (vr & 7)) << 3)];
            o[0][c] = mfma16(pa[0][h2], vb, o[0][c]);
            o[1][c] = mfma16(pa[1][h2], vb, o[1][c]);
          }
        }
        __builtin_amdgcn_s_setprio(0);
      }
      __syncthreads();
    }

    // ---- epilogue: divide by l (redistributed), store ----
    float linv[2];
#pragma unroll
    for (int mB = 0; mB < 2; mB++) linv[mB] = 1.0f / lrun[mB];
    float li[2][4];
#pragma unroll
    for (int j = 0; j < 4; j++) {
      li[0][j] = __shfl(linv[0], g * 4 + j);
      li[1][j] = __shfl(linv[1], g * 4 + j);
    }
#pragma unroll
    for (int m = 0; m < 2; m++)
#pragma unroll
      for (int c = 0; c < 4; c++)
#pragma unroll
        for (int j = 0; j < 4; j++) {
          int q = qw0 + m * 16 + g * 4 + j, d = c * 16 + r16;
          ctx[((size_t)(b * TT + q)) * DK + h * HD + d] = (bf16_t)(o[m][c][j] * li[m][j]);
        }
  };

  run_qtile(blockIdx.x);       // light tile (x in 0..7)
  run_qtile(15 - blockIdx.x);  // heavy tile -> constant total work per block
}

// ---------------------------------------------------------------------------
extern "C" void kernel_launch(void* const* d_in, const int* in_sizes, int n_in,
                              void* d_out, int out_size, void* d_ws, size_t ws_size,
                              hipStream_t stream) {
  const float* x = (const float*)d_in[0];
  const float* Wq = (const float*)d_in[1];
  const float* Wk = (const float*)d_in[2];
  const float* Wv = (const float*)d_in[3];
  const float* Wo = (const float*)d_in[4];
  const float* bo = (const float*)d_in[5];
  float* out = (float*)d_out;

  char* ws = (char*)d_ws;
  const size_t MB = 1u << 20;
  bf16_t* xb    = (bf16_t*)(ws + 0 * MB);    // 16 MB
  bf16_t* Wqkvt = (bf16_t*)(ws + 16 * MB);   // 6 MB: [3][1024][1024] N-major
  bf16_t* Wot   = (bf16_t*)(ws + 22 * MB);   // 2 MB
  bf16_t* Qb    = (bf16_t*)(ws + 24 * MB);   // 16 MB [b,h,t,d]
  bf16_t* Kb    = (bf16_t*)(ws + 40 * MB);   // 16 MB [b,h,t,d]
  bf16_t* Vtb   = (bf16_t*)(ws + 56 * MB);   // 16 MB [b,h,d,t]
  bf16_t* ctx   = (bf16_t*)(ws + 72 * MB);   // 16 MB [b,t,h*64+d]

  const int M = BB * TT;  // 8192

  cast_x_kernel<<<(M * DK / 8 + 255) / 256, 256, 0, stream>>>(x, xb, M * DK / 8);

  transpose_cast4_kernel<<<dim3(32, 32, 4), dim3(32, 8), 0, stream>>>(
      Wq, Wk, Wv, Wo, Wqkvt, Wot);

  // fused QKV: 8192 x 3072 x 1024
  gemm_bt<0><<<dim3(3 * DK / 128, M / 128), 256, 0, stream>>>(
      xb, Wqkvt, Qb, Kb, Vtb, nullptr, M, 3 * DK, DK);

  attn_fwd<<<dim3(TT / 256, BB * NH), 256, 0, stream>>>(Qb, Kb, Vtb, ctx);

  gemm_bt<2><<<dim3(DK / 128, M / 128), 256, 0, stream>>>(
      ctx, Wot, out, nullptr, nullptr, bo, M, DK, DK);
}

// Round 7
// 272.260 us; speedup vs baseline: 2.1535x; 1.0133x over previous
//
#include <hip/hip_runtime.h>

// ---------------------------------------------------------------------------
// MultiHeadedAttention forward, bf16 MFMA implementation. Round 7.
// B=4, T=2048, DIN=DOUT=1024, H=16, HD=64. Causal softmax, eval (no dropout).
// ---------------------------------------------------------------------------

typedef __bf16 bf16_t;
typedef __bf16 bf16x4 __attribute__((ext_vector_type(4)));
typedef __bf16 bf16x8 __attribute__((ext_vector_type(8)));
typedef float f32x4 __attribute__((ext_vector_type(4)));

#define BB 4
#define TT 2048
#define DK 1024
#define NH 16
#define HD 64

static __device__ __forceinline__ f32x4 mfma16(bf16x8 a, bf16x8 b, f32x4 c) {
  return __builtin_amdgcn_mfma_f32_16x16x32_bf16(a, b, c, 0, 0, 0);
}

// 2^x via v_exp_f32 directly (avoids glibc __exp2f macro collision).
static __device__ __forceinline__ float exp2_hw(float x) {
  return __builtin_amdgcn_exp2f(x);
}

typedef __attribute__((address_space(1))) const unsigned int as1_uint;
typedef __attribute__((address_space(3))) unsigned int as3_uint;
static __device__ __forceinline__ void gload_lds16(const bf16_t* g, bf16_t* l) {
  __builtin_amdgcn_global_load_lds((as1_uint*)g, (as3_uint*)l, 16, 0, 0);
}

// ---- cast x (fp32) -> bf16, 8 elems/thread ---------------------------------
__global__ __launch_bounds__(256) void cast_x_kernel(const float* __restrict__ in,
                                                     bf16_t* __restrict__ out, int n8) {
  int i = blockIdx.x * blockDim.x + threadIdx.x;
  if (i < n8) {
    const float4* p = (const float4*)(in + (size_t)i * 8);
    float4 u = p[0], v = p[1];
    bf16x8 o = {(__bf16)u.x, (__bf16)u.y, (__bf16)u.z, (__bf16)u.w,
                (__bf16)v.x, (__bf16)v.y, (__bf16)v.z, (__bf16)v.w};
    *(bf16x8*)(out + (size_t)i * 8) = o;
  }
}

// ---- transpose + cast all 4 weights in one launch (z selects matrix) -------
__global__ __launch_bounds__(256) void transpose_cast4_kernel(
    const float* __restrict__ W0, const float* __restrict__ W1,
    const float* __restrict__ W2, const float* __restrict__ W3,
    bf16_t* __restrict__ dstQKV, bf16_t* __restrict__ dstO) {
  __shared__ float tile[32][33];
  const int z = blockIdx.z;
  const float* W = (z == 0) ? W0 : (z == 1) ? W1 : (z == 2) ? W2 : W3;
  bf16_t* Wt = (z < 3) ? dstQKV + (size_t)z * DK * DK : dstO;
  int bx = blockIdx.x * 32;
  int by = blockIdx.y * 32;
  int tx = threadIdx.x, ty = threadIdx.y;  // 32 x 8
#pragma unroll
  for (int i = 0; i < 32; i += 8)
    tile[ty + i][tx] = W[(size_t)(by + ty + i) * DK + bx + tx];
  __syncthreads();
#pragma unroll
  for (int i = 0; i < 32; i += 8)
    Wt[(size_t)(bx + ty + i) * DK + by + tx] = (bf16_t)tile[tx][ty + i];
}

// ---- GEMM, min-2-phase pipelined: C[M][N] = A[M][K] * Bt[N][K]^T -----------
// 128x128 tile, BK=32, 256 threads = 4 waves (2x2), each wave 64x64 (4x4).
// LDS double-buffered; stage(next) issued BEFORE compute(cur); one barrier/iter
// so global_load_lds overlaps ds_read+MFMA. setprio(1) around MFMA cluster.
// MODE 0: fused QKV (N=3072): proj=n0>>10 -> Q/K: bf16 [b,h,t,d]; V: [b,h,d,t]
//         Q is PRE-SCALED by 0.125*log2(e) (softmax exp2-domain fold).
// MODE 2: fp32 + bias at [row][col]
template <int MODE>
__global__ __launch_bounds__(256) void gemm_bt(const bf16_t* __restrict__ A,
                                               const bf16_t* __restrict__ Bt,
                                               void* __restrict__ out0,
                                               void* __restrict__ out1,
                                               void* __restrict__ out2,
                                               const float* __restrict__ bias,
                                               int M, int N, int K) {
  __shared__ __align__(16) bf16_t As[2][128 * 32];
  __shared__ __align__(16) bf16_t Bs[2][128 * 32];
  const int tid = threadIdx.x;
  const int w = tid >> 6, lane = tid & 63, g = lane >> 4, r16 = lane & 15;
  const int m0 = blockIdx.y * 128, n0 = blockIdx.x * 128;
  const int wr = (w >> 1) * 64, wc = (w & 1) * 64;

  const int srow = w * 32 + (lane >> 2);
  const int scol = (lane & 3) * 8;
  const bf16_t* Asrc = A + (size_t)(m0 + srow) * K + scol;
  const bf16_t* Bsrc = Bt + (size_t)(n0 + srow) * K + scol;

  auto stage = [&](int k0, int buf) {
    gload_lds16(Asrc + k0, &As[buf][(w * 32) * 32]);
    gload_lds16(Asrc + k0 + (size_t)16 * K, &As[buf][(w * 32 + 16) * 32]);
    gload_lds16(Bsrc + k0, &Bs[buf][(w * 32) * 32]);
    gload_lds16(Bsrc + k0 + (size_t)16 * K, &Bs[buf][(w * 32 + 16) * 32]);
  };

  f32x4 acc[4][4] = {};

  stage(0, 0);
  asm volatile("s_waitcnt vmcnt(0)" ::: "memory");
  __syncthreads();

  int cur = 0;
  for (int k0 = 0; k0 < K; k0 += 32) {
    if (k0 + 32 < K) stage(k0 + 32, cur ^ 1);  // issue loads early: overlap

    bf16x8 a[4], b[4];
#pragma unroll
    for (int m = 0; m < 4; m++)
      a[m] = *(bf16x8*)&As[cur][(wr + m * 16 + r16) * 32 + g * 8];
#pragma unroll
    for (int n = 0; n < 4; n++)
      b[n] = *(bf16x8*)&Bs[cur][(wc + n * 16 + r16) * 32 + g * 8];

    __builtin_amdgcn_s_setprio(1);
#pragma unroll
    for (int m = 0; m < 4; m++)
#pragma unroll
      for (int n = 0; n < 4; n++) acc[m][n] = mfma16(a[m], b[n], acc[m][n]);
    __builtin_amdgcn_s_setprio(0);

    asm volatile("s_waitcnt vmcnt(0)" ::: "memory");
    __syncthreads();
    cur ^= 1;
  }

  const float QSC = 0.18033688011112042f;  // 0.125 * log2(e), folded into Q
  const int proj = n0 >> 10;  // MODE 0: which of Q/K/V (tiles never straddle)
  if (MODE == 0 && proj == 2) {
    // V^T: the 4 j-values are t-contiguous -> one 8B store per fragment.
#pragma unroll
    for (int m = 0; m < 4; m++)
#pragma unroll
      for (int n = 0; n < 4; n++) {
        int row0 = m0 + wr + m * 16 + g * 4;
        int col = (n0 + wc + n * 16 + r16) & (DK - 1);
        int b_ = row0 >> 11, t0 = row0 & (TT - 1), h = col >> 6, d = col & 63;
        bf16x4 pk = {(bf16_t)acc[m][n][0], (bf16_t)acc[m][n][1],
                     (bf16_t)acc[m][n][2], (bf16_t)acc[m][n][3]};
        *(bf16x4*)&((bf16_t*)out2)[((size_t)(b_ * NH + h) * HD + d) * TT + t0] = pk;
      }
  } else {
#pragma unroll
    for (int m = 0; m < 4; m++)
#pragma unroll
      for (int n = 0; n < 4; n++)
#pragma unroll
        for (int j = 0; j < 4; j++) {
          int row = m0 + wr + m * 16 + g * 4 + j;
          int colg = n0 + wc + n * 16 + r16;
          float v = acc[m][n][j];
          if (MODE == 0) {
            int col = colg & (DK - 1);
            int b_ = row >> 11, t = row & (TT - 1), h = col >> 6, d = col & 63;
            if (proj == 0)
              ((bf16_t*)out0)[(((size_t)(b_ * NH + h) * TT + t) << 6) + d] =
                  (bf16_t)(v * QSC);
            else
              ((bf16_t*)out1)[(((size_t)(b_ * NH + h) * TT + t) << 6) + d] = (bf16_t)v;
          } else {
            ((float*)out0)[(size_t)row * N + colg] = v + bias[colg];
          }
        }
  }
}

// ---- causal flash attention v4 ---------------------------------------------
// 256 threads = 4 waves; q-block = 128 rows (32/wave); KV tile = 64 keys.
// 1-D grid of 512 blocks, XCD-locality mapped: bid&7 selects XCD; the 8
// q-tile-pair blocks of one (b,h) land on the SAME XCD, co-resident -> K/V
// served from that XCD's L2 (512 KB/head << 4 MB).
// Pair-balanced: block does q-tiles {qp, 15-qp} (34 key-tiles each).
// Swapped QK^T (S^T = mfma(K,Q)); exp2-domain softmax, Q pre-scaled;
// defer-max (THR=8): skip rescale when tile max growth <= 8.
__global__ __launch_bounds__(256) void attn_fwd(const bf16_t* __restrict__ Q,
                                                const bf16_t* __restrict__ K,
                                                const bf16_t* __restrict__ Vt,
                                                bf16_t* __restrict__ ctx) {
  __shared__ __align__(16) bf16_t Ks[2][64 * 64];
  __shared__ __align__(16) bf16_t Vs[2][64 * 64];
  __shared__ __align__(16) bf16_t Ps[4][32][72];

  const int tid = threadIdx.x;
  const int w = tid >> 6, lane = tid & 63, g = lane >> 4, r16 = lane & 15;
  // XCD-locality decomposition of the 512-block grid:
  const int bid = blockIdx.x;
  const int bh = (bid & 7) * 8 + ((bid >> 3) & 7);  // same bh -> same bid%8 -> same XCD
  const int qp = bid >> 6;                          // q-tile pair 0..7
  const int b = bh >> 4, h = bh & (NH - 1);

  const bf16_t* Qp = Q + (size_t)bh * TT * HD;
  const bf16_t* Kp = K + (size_t)bh * TT * HD;
  const bf16_t* Vp = Vt + (size_t)bh * HD * TT;

  const int sr_lo = (lane >> 3);
  const int sc = lane & 7;
  auto stage = [&](int kt, int buf) {
    const int k0s = kt * 64;
#pragma unroll
    for (int j = 0; j < 2; j++) {
      int r = w * 16 + j * 8 + sr_lo;
      int cs = ((sc ^ (r & 7)) << 3);
      gload_lds16(Kp + (size_t)(k0s + r) * HD + cs, &Ks[buf][(w * 16 + j * 8) * 64]);
      gload_lds16(Vp + (size_t)r * TT + k0s + cs, &Vs[buf][(w * 16 + j * 8) * 64]);
    }
  };

  auto run_qtile = [&](int qt) {
    const int q0 = qt * 128, qw0 = q0 + w * 32;
    bf16x8 qf[2][2];
#pragma unroll
    for (int m = 0; m < 2; m++)
#pragma unroll
      for (int hh = 0; hh < 2; hh++)
        qf[m][hh] = *(const bf16x8*)&Qp[(size_t)(qw0 + m * 16 + r16) * HD + hh * 32 + g * 8];

    float mrun[2] = {-1e30f, -1e30f}, lrun[2] = {0.f, 0.f};
    f32x4 o[2][4] = {};

    const int nkt = 2 * (qt + 1);  // always even
    const int wmax = qw0 + 31;

    stage(0, 0);
    __syncthreads();

    for (int kt = 0; kt < nkt; kt++) {
      const int cur = kt & 1;
      if (kt + 1 < nkt) stage(kt + 1, cur ^ 1);
      const int k0 = kt * 64;

      if (k0 <= wmax) {
        // ---- S^T = K Q^T : lane owns q = qw0+mB*16+r16, k = k0+a*16+g*4+j --
        f32x4 sT[4][2];
        __builtin_amdgcn_s_setprio(1);
#pragma unroll
        for (int a = 0; a < 4; a++) {
          int kr = a * 16 + r16;
          bf16x8 kb0 = *(bf16x8*)&Ks[cur][kr * 64 + ((g ^ (kr & 7)) << 3)];
          bf16x8 kb1 = *(bf16x8*)&Ks[cur][kr * 64 + (((4 + g) ^ (kr & 7)) << 3)];
#pragma unroll
          for (int mB = 0; mB < 2; mB++) {
            f32x4 z = {0.f, 0.f, 0.f, 0.f};
            sT[a][mB] = mfma16(kb1, qf[mB][1], mfma16(kb0, qf[mB][0], z));
          }
        }
        __builtin_amdgcn_s_setprio(0);
        // ---- (Q pre-scaled; p already in exp2 domain) + causal mask --------
        float p[2][4][4];
#pragma unroll
        for (int mB = 0; mB < 2; mB++)
#pragma unroll
          for (int a = 0; a < 4; a++)
#pragma unroll
            for (int j = 0; j < 4; j++) p[mB][a][j] = sT[a][mB][j];
        // Mask unless the whole tile is below the diagonal for EVERY row of
        // this wave: safe iff k0+63 <= qw0 (min q row).
        if (k0 + 63 > qw0) {
#pragma unroll
          for (int mB = 0; mB < 2; mB++) {
            int qq = qw0 + mB * 16 + r16;
#pragma unroll
            for (int a = 0; a < 4; a++)
#pragma unroll
              for (int j = 0; j < 4; j++) {
                int kq = k0 + a * 16 + g * 4 + j;
                if (kq > qq) p[mB][a][j] = -1e30f;
              }
          }
        }
        // ---- online softmax, exp2 domain, defer-max (THR=8) ----
        bool resc[2];
        float fac[2];
#pragma unroll
        for (int mB = 0; mB < 2; mB++) {
          float ta[4], sa[4];
#pragma unroll
          for (int a = 0; a < 4; a++)
            ta[a] = fmaxf(fmaxf(p[mB][a][0], p[mB][a][1]),
                          fmaxf(p[mB][a][2], p[mB][a][3]));
          float t = fmaxf(fmaxf(ta[0], ta[1]), fmaxf(ta[2], ta[3]));
          t = fmaxf(t, __shfl_xor(t, 16));
          t = fmaxf(t, __shfl_xor(t, 32));
          // defer-max: keep old reference max unless growth exceeds 8
          // (P values then bounded by 2^8=256 -- fine in bf16/f32).
          bool skip = __all(t - mrun[mB] <= 8.0f);
          resc[mB] = !skip;
          float mn = skip ? mrun[mB] : fmaxf(mrun[mB], t);
#pragma unroll
          for (int a = 0; a < 4; a++) {
#pragma unroll
            for (int j = 0; j < 4; j++) p[mB][a][j] = exp2_hw(p[mB][a][j] - mn);
            sa[a] = (p[mB][a][0] + p[mB][a][1]) + (p[mB][a][2] + p[mB][a][3]);
          }
          float rs = (sa[0] + sa[1]) + (sa[2] + sa[3]);
          rs += __shfl_xor(rs, 16);
          rs += __shfl_xor(rs, 32);
          if (skip) {
            lrun[mB] += rs;
          } else {
            fac[mB] = exp2_hw(mrun[mB] - mn);
            lrun[mB] = lrun[mB] * fac[mB] + rs;
            mrun[mB] = mn;
          }
        }
        // ---- P -> Ps (packed b64 writes) ----
#pragma unroll
        for (int mB = 0; mB < 2; mB++)
#pragma unroll
          for (int a = 0; a < 4; a++) {
            bf16x4 pk = {(__bf16)p[mB][a][0], (__bf16)p[mB][a][1],
                         (__bf16)p[mB][a][2], (__bf16)p[mB][a][3]};
            *(bf16x4*)&Ps[w][mB * 16 + r16][a * 16 + g * 4] = pk;
          }
        // ---- redistribute fac to O layout, rescale (only when max moved) --
#pragma unroll
        for (int mB = 0; mB < 2; mB++)
          if (resc[mB]) {  // wave-uniform
            float fj[4];
#pragma unroll
            for (int j = 0; j < 4; j++) fj[j] = __shfl(fac[mB], g * 4 + j);
#pragma unroll
            for (int c = 0; c < 4; c++)
#pragma unroll
              for (int j = 0; j < 4; j++) o[mB][c][j] *= fj[j];
          }
        asm volatile("s_waitcnt lgkmcnt(0)" ::: "memory");
        bf16x8 pa[2][2];
#pragma unroll
        for (int m = 0; m < 2; m++)
#pragma unroll
          for (int h2 = 0; h2 < 2; h2++)
            pa[m][h2] = *(bf16x8*)&Ps[w][m * 16 + r16][h2 * 32 + g * 8];
        // ---- O += P V ----
        __builtin_amdgcn_s_setprio(1);
#pragma unroll
        for (int c = 0; c < 4; c++) {
          int vr = c * 16 + r16;
#pragma unroll
          for (int h2 = 0; h2 < 2; h2++) {
            bf16x8 vb = *(bf16x8*)&Vs[cur][vr * 64 + (((4 * h2 + g) ^ (vr & 7)) << 3)];
            o[0][c] = mfma16(pa[0][h2], vb, o[0][c]);
            o[1][c] = mfma16(pa[1][h2], vb, o[1][c]);
          }
        }
        __builtin_amdgcn_s_setprio(0);
      }
      __syncthreads();
    }

    // ---- epilogue: divide by l (redistributed), store ----
    float linv[2];
#pragma unroll
    for (int mB = 0; mB < 2; mB++) linv[mB] = 1.0f / lrun[mB];
    float li[2][4];
#pragma unroll
    for (int j = 0; j < 4; j++) {
      li[0][j] = __shfl(linv[0], g * 4 + j);
      li[1][j] = __shfl(linv[1], g * 4 + j);
    }
#pragma unroll
    for (int m = 0; m < 2; m++)
#pragma unroll
      for (int c = 0; c < 4; c++)
#pragma unroll
        for (int j = 0; j < 4; j++) {
          int q = qw0 + m * 16 + g * 4 + j, d = c * 16 + r16;
          ctx[((size_t)(b * TT + q)) * DK + h * HD + d] = (bf16_t)(o[m][c][j] * li[m][j]);
        }
  };

  run_qtile(qp);       // light tile (qp in 0..7)
  run_qtile(15 - qp);  // heavy tile -> constant total work per block
}

// ---------------------------------------------------------------------------
extern "C" void kernel_launch(void* const* d_in, const int* in_sizes, int n_in,
                              void* d_out, int out_size, void* d_ws, size_t ws_size,
                              hipStream_t stream) {
  const float* x = (const float*)d_in[0];
  const float* Wq = (const float*)d_in[1];
  const float* Wk = (const float*)d_in[2];
  const float* Wv = (const float*)d_in[3];
  const float* Wo = (const float*)d_in[4];
  const float* bo = (const float*)d_in[5];
  float* out = (float*)d_out;

  char* ws = (char*)d_ws;
  const size_t MB = 1u << 20;
  bf16_t* xb    = (bf16_t*)(ws + 0 * MB);    // 16 MB
  bf16_t* Wqkvt = (bf16_t*)(ws + 16 * MB);   // 6 MB: [3][1024][1024] N-major
  bf16_t* Wot   = (bf16_t*)(ws + 22 * MB);   // 2 MB
  bf16_t* Qb    = (bf16_t*)(ws + 24 * MB);   // 16 MB [b,h,t,d] (pre-scaled)
  bf16_t* Kb    = (bf16_t*)(ws + 40 * MB);   // 16 MB [b,h,t,d]
  bf16_t* Vtb   = (bf16_t*)(ws + 56 * MB);   // 16 MB [b,h,d,t]
  bf16_t* ctx   = (bf16_t*)(ws + 72 * MB);   // 16 MB [b,t,h*64+d]

  const int M = BB * TT;  // 8192

  cast_x_kernel<<<(M * DK / 8 + 255) / 256, 256, 0, stream>>>(x, xb, M * DK / 8);

  transpose_cast4_kernel<<<dim3(32, 32, 4), dim3(32, 8), 0, stream>>>(
      Wq, Wk, Wv, Wo, Wqkvt, Wot);

  // fused QKV: 8192 x 3072 x 1024
  gemm_bt<0><<<dim3(3 * DK / 128, M / 128), 256, 0, stream>>>(
      xb, Wqkvt, Qb, Kb, Vtb, nullptr, M, 3 * DK, DK);

  attn_fwd<<<512, 256, 0, stream>>>(Qb, Kb, Vtb, ctx);

  gemm_bt<2><<<dim3(DK / 128, M / 128), 256, 0, stream>>>(
      ctx, Wot, out, nullptr, nullptr, bo, M, DK, DK);
}

// Round 8
// 264.502 us; speedup vs baseline: 2.2166x; 1.0293x over previous
//
#include <hip/hip_runtime.h>

// ---------------------------------------------------------------------------
// MultiHeadedAttention forward, bf16 MFMA implementation. Round 8.
// B=4, T=2048, DIN=DOUT=1024, H=16, HD=64. Causal softmax, eval (no dropout).
// ---------------------------------------------------------------------------

typedef __bf16 bf16_t;
typedef __bf16 bf16x4 __attribute__((ext_vector_type(4)));
typedef __bf16 bf16x8 __attribute__((ext_vector_type(8)));
typedef float f32x4 __attribute__((ext_vector_type(4)));

#define BB 4
#define TT 2048
#define DK 1024
#define NH 16
#define HD 64

static __device__ __forceinline__ f32x4 mfma16(bf16x8 a, bf16x8 b, f32x4 c) {
  return __builtin_amdgcn_mfma_f32_16x16x32_bf16(a, b, c, 0, 0, 0);
}

// 2^x via v_exp_f32 directly (avoids glibc __exp2f macro collision).
static __device__ __forceinline__ float exp2_hw(float x) {
  return __builtin_amdgcn_exp2f(x);
}

typedef __attribute__((address_space(1))) const unsigned int as1_uint;
typedef __attribute__((address_space(3))) unsigned int as3_uint;
static __device__ __forceinline__ void gload_lds16(const bf16_t* g, bf16_t* l) {
  __builtin_amdgcn_global_load_lds((as1_uint*)g, (as3_uint*)l, 16, 0, 0);
}

// ---- cast x (fp32) -> bf16, 8 elems/thread ---------------------------------
__global__ __launch_bounds__(256) void cast_x_kernel(const float* __restrict__ in,
                                                     bf16_t* __restrict__ out, int n8) {
  int i = blockIdx.x * blockDim.x + threadIdx.x;
  if (i < n8) {
    const float4* p = (const float4*)(in + (size_t)i * 8);
    float4 u = p[0], v = p[1];
    bf16x8 o = {(__bf16)u.x, (__bf16)u.y, (__bf16)u.z, (__bf16)u.w,
                (__bf16)v.x, (__bf16)v.y, (__bf16)v.z, (__bf16)v.w};
    *(bf16x8*)(out + (size_t)i * 8) = o;
  }
}

// ---- transpose + cast all 4 weights in one launch (z selects matrix) -------
__global__ __launch_bounds__(256) void transpose_cast4_kernel(
    const float* __restrict__ W0, const float* __restrict__ W1,
    const float* __restrict__ W2, const float* __restrict__ W3,
    bf16_t* __restrict__ dstQKV, bf16_t* __restrict__ dstO) {
  __shared__ float tile[32][33];
  const int z = blockIdx.z;
  const float* W = (z == 0) ? W0 : (z == 1) ? W1 : (z == 2) ? W2 : W3;
  bf16_t* Wt = (z < 3) ? dstQKV + (size_t)z * DK * DK : dstO;
  int bx = blockIdx.x * 32;
  int by = blockIdx.y * 32;
  int tx = threadIdx.x, ty = threadIdx.y;  // 32 x 8
#pragma unroll
  for (int i = 0; i < 32; i += 8)
    tile[ty + i][tx] = W[(size_t)(by + ty + i) * DK + bx + tx];
  __syncthreads();
#pragma unroll
  for (int i = 0; i < 32; i += 8)
    Wt[(size_t)(bx + ty + i) * DK + by + tx] = (bf16_t)tile[tx][ty + i];
}

// ---- GEMM, 3-buffer counted-vmcnt pipeline: C = A[M][K] * Bt[N][K]^T -------
// 128x128 tile, BK=32, 256 threads = 4 waves (2x2), each wave 64x64 (4x4).
// Two stages in flight; per-iter s_waitcnt vmcnt(4) waits only the OLDEST
// tile's own-wave loads; raw s_barrier (no vmcnt(0) drain). Each wave stages
// its own LDS quarter, so own-wave vmcnt + barrier => tile fully resident.
// Buffer overwritten by stage(t+2) was ds_read in iter t-1; those reads drain
// (MFMA data-dep) before that wave reaches the iter-t barrier -> race-free.
// MODE 0: fused QKV (N=3072): proj=n0>>10 -> Q/K: bf16 [b,h,t,d]; V: [b,h,d,t]
//         Q is PRE-SCALED by 0.125*log2(e) (softmax exp2-domain fold).
// MODE 2: fp32 + bias at [row][col]
template <int MODE>
__global__ __launch_bounds__(256) void gemm_bt(const bf16_t* __restrict__ A,
                                               const bf16_t* __restrict__ Bt,
                                               void* __restrict__ out0,
                                               void* __restrict__ out1,
                                               void* __restrict__ out2,
                                               const float* __restrict__ bias,
                                               int M, int N, int K) {
  __shared__ __align__(16) bf16_t As[3][128 * 32];
  __shared__ __align__(16) bf16_t Bs[3][128 * 32];
  const int tid = threadIdx.x;
  const int w = tid >> 6, lane = tid & 63, g = lane >> 4, r16 = lane & 15;
  const int m0 = blockIdx.y * 128, n0 = blockIdx.x * 128;
  const int wr = (w >> 1) * 64, wc = (w & 1) * 64;

  const int srow = w * 32 + (lane >> 2);
  const int scol = (lane & 3) * 8;
  const bf16_t* Asrc = A + (size_t)(m0 + srow) * K + scol;
  const bf16_t* Bsrc = Bt + (size_t)(n0 + srow) * K + scol;

  auto stage = [&](int k0, int buf) {
    gload_lds16(Asrc + k0, &As[buf][(w * 32) * 32]);
    gload_lds16(Asrc + k0 + (size_t)16 * K, &As[buf][(w * 32 + 16) * 32]);
    gload_lds16(Bsrc + k0, &Bs[buf][(w * 32) * 32]);
    gload_lds16(Bsrc + k0 + (size_t)16 * K, &Bs[buf][(w * 32 + 16) * 32]);
  };

  f32x4 acc[4][4] = {};
  const int NT = K >> 5;  // 32 for K=1024

  stage(0, 0);
  stage(32, 1);

  int cur = 0;
  for (int t = 0; t < NT; ++t) {
    // wait oldest in-flight tile (own 4 loads); keep newer tile in flight
    if (t + 1 < NT) {
      asm volatile("s_waitcnt vmcnt(4)" ::: "memory");
    } else {
      asm volatile("s_waitcnt vmcnt(0)" ::: "memory");
    }
    __builtin_amdgcn_s_barrier();
    asm volatile("" ::: "memory");  // keep stage below the barrier

    if (t + 2 < NT) {
      int sb = cur + 2; if (sb >= 3) sb -= 3;
      stage((t + 2) << 5, sb);
    }

    bf16x8 a[4], b[4];
#pragma unroll
    for (int m = 0; m < 4; m++)
      a[m] = *(bf16x8*)&As[cur][(wr + m * 16 + r16) * 32 + g * 8];
#pragma unroll
    for (int n = 0; n < 4; n++)
      b[n] = *(bf16x8*)&Bs[cur][(wc + n * 16 + r16) * 32 + g * 8];

    __builtin_amdgcn_s_setprio(1);
#pragma unroll
    for (int m = 0; m < 4; m++)
#pragma unroll
      for (int n = 0; n < 4; n++) acc[m][n] = mfma16(a[m], b[n], acc[m][n]);
    __builtin_amdgcn_s_setprio(0);

    cur++; if (cur == 3) cur = 0;
  }

  const float QSC = 0.18033688011112042f;  // 0.125 * log2(e), folded into Q
  const int proj = n0 >> 10;  // MODE 0: which of Q/K/V (tiles never straddle)
  if (MODE == 0 && proj == 2) {
    // V^T: the 4 j-values are t-contiguous -> one 8B store per fragment.
#pragma unroll
    for (int m = 0; m < 4; m++)
#pragma unroll
      for (int n = 0; n < 4; n++) {
        int row0 = m0 + wr + m * 16 + g * 4;
        int col = (n0 + wc + n * 16 + r16) & (DK - 1);
        int b_ = row0 >> 11, t0 = row0 & (TT - 1), h = col >> 6, d = col & 63;
        bf16x4 pk = {(bf16_t)acc[m][n][0], (bf16_t)acc[m][n][1],
                     (bf16_t)acc[m][n][2], (bf16_t)acc[m][n][3]};
        *(bf16x4*)&((bf16_t*)out2)[((size_t)(b_ * NH + h) * HD + d) * TT + t0] = pk;
      }
  } else {
#pragma unroll
    for (int m = 0; m < 4; m++)
#pragma unroll
      for (int n = 0; n < 4; n++)
#pragma unroll
        for (int j = 0; j < 4; j++) {
          int row = m0 + wr + m * 16 + g * 4 + j;
          int colg = n0 + wc + n * 16 + r16;
          float v = acc[m][n][j];
          if (MODE == 0) {
            int col = colg & (DK - 1);
            int b_ = row >> 11, t = row & (TT - 1), h = col >> 6, d = col & 63;
            if (proj == 0)
              ((bf16_t*)out0)[(((size_t)(b_ * NH + h) * TT + t) << 6) + d] =
                  (bf16_t)(v * QSC);
            else
              ((bf16_t*)out1)[(((size_t)(b_ * NH + h) * TT + t) << 6) + d] = (bf16_t)v;
          } else {
            ((float*)out0)[(size_t)row * N + colg] = v + bias[colg];
          }
        }
  }
}

// ---- causal flash attention v5 ---------------------------------------------
// 256 threads = 4 waves; q-block = 128 rows (32/wave); KV tile = 64 keys.
// Grid 1024 = 16 q-tiles x 64 bh, 1 q-tile per block, heavy tiles dispatch
// first (qt = 15 - bid>>6). XCD-locality: bid&7 fixes the XCD; all 16 blocks
// of one (b,h) share bid&7 -> K/V served from that XCD's L2 (proven R7:
// FETCH 147->25 MB). 3 blocks/CU resident (51.2 KB LDS).
// Swapped QK^T (S^T = mfma(K,Q)); exp2-domain softmax, Q pre-scaled;
// defer-max (THR=8): skip rescale when tile max growth <= 8.
__global__ __launch_bounds__(256) void attn_fwd(const bf16_t* __restrict__ Q,
                                                const bf16_t* __restrict__ K,
                                                const bf16_t* __restrict__ Vt,
                                                bf16_t* __restrict__ ctx) {
  __shared__ __align__(16) bf16_t Ks[2][64 * 64];
  __shared__ __align__(16) bf16_t Vs[2][64 * 64];
  __shared__ __align__(16) bf16_t Ps[4][32][72];

  const int tid = threadIdx.x;
  const int w = tid >> 6, lane = tid & 63, g = lane >> 4, r16 = lane & 15;
  const int bid = blockIdx.x;
  const int bh = (bid & 7) * 8 + ((bid >> 3) & 7);  // same bh -> same XCD
  const int qt = 15 - (bid >> 6);                   // heavy q-tiles first
  const int b = bh >> 4, h = bh & (NH - 1);

  const bf16_t* Qp = Q + (size_t)bh * TT * HD;
  const bf16_t* Kp = K + (size_t)bh * TT * HD;
  const bf16_t* Vp = Vt + (size_t)bh * HD * TT;

  const int sr_lo = (lane >> 3);
  const int sc = lane & 7;
  auto stage = [&](int kt, int buf) {
    const int k0s = kt * 64;
#pragma unroll
    for (int j = 0; j < 2; j++) {
      int r = w * 16 + j * 8 + sr_lo;
      int cs = ((sc ^ (r & 7)) << 3);
      gload_lds16(Kp + (size_t)(k0s + r) * HD + cs, &Ks[buf][(w * 16 + j * 8) * 64]);
      gload_lds16(Vp + (size_t)r * TT + k0s + cs, &Vs[buf][(w * 16 + j * 8) * 64]);
    }
  };

  const int q0 = qt * 128, qw0 = q0 + w * 32;
  bf16x8 qf[2][2];
#pragma unroll
  for (int m = 0; m < 2; m++)
#pragma unroll
    for (int hh = 0; hh < 2; hh++)
      qf[m][hh] = *(const bf16x8*)&Qp[(size_t)(qw0 + m * 16 + r16) * HD + hh * 32 + g * 8];

  float mrun[2] = {-1e30f, -1e30f}, lrun[2] = {0.f, 0.f};
  f32x4 o[2][4] = {};

  const int nkt = 2 * (qt + 1);
  const int wmax = qw0 + 31;

  stage(0, 0);
  __syncthreads();

  for (int kt = 0; kt < nkt; kt++) {
    const int cur = kt & 1;
    if (kt + 1 < nkt) stage(kt + 1, cur ^ 1);
    const int k0 = kt * 64;

    if (k0 <= wmax) {
      // ---- S^T = K Q^T : lane owns q = qw0+mB*16+r16, k = k0+a*16+g*4+j ----
      f32x4 sT[4][2];
      __builtin_amdgcn_s_setprio(1);
#pragma unroll
      for (int a = 0; a < 4; a++) {
        int kr = a * 16 + r16;
        bf16x8 kb0 = *(bf16x8*)&Ks[cur][kr * 64 + ((g ^ (kr & 7)) << 3)];
        bf16x8 kb1 = *(bf16x8*)&Ks[cur][kr * 64 + (((4 + g) ^ (kr & 7)) << 3)];
#pragma unroll
        for (int mB = 0; mB < 2; mB++) {
          f32x4 z = {0.f, 0.f, 0.f, 0.f};
          sT[a][mB] = mfma16(kb1, qf[mB][1], mfma16(kb0, qf[mB][0], z));
        }
      }
      __builtin_amdgcn_s_setprio(0);
      // ---- (Q pre-scaled; p already in exp2 domain) + causal mask ----------
      float p[2][4][4];
#pragma unroll
      for (int mB = 0; mB < 2; mB++)
#pragma unroll
        for (int a = 0; a < 4; a++)
#pragma unroll
          for (int j = 0; j < 4; j++) p[mB][a][j] = sT[a][mB][j];
      // Mask unless whole tile below diagonal for EVERY row: k0+63 <= qw0.
      if (k0 + 63 > qw0) {
#pragma unroll
        for (int mB = 0; mB < 2; mB++) {
          int qq = qw0 + mB * 16 + r16;
#pragma unroll
          for (int a = 0; a < 4; a++)
#pragma unroll
            for (int j = 0; j < 4; j++) {
              int kq = k0 + a * 16 + g * 4 + j;
              if (kq > qq) p[mB][a][j] = -1e30f;
            }
        }
      }
      // ---- online softmax, exp2 domain, defer-max (THR=8) ----
      bool resc[2];
      float fac[2];
#pragma unroll
      for (int mB = 0; mB < 2; mB++) {
        float ta[4], sa[4];
#pragma unroll
        for (int a = 0; a < 4; a++)
          ta[a] = fmaxf(fmaxf(p[mB][a][0], p[mB][a][1]),
                        fmaxf(p[mB][a][2], p[mB][a][3]));
        float t = fmaxf(fmaxf(ta[0], ta[1]), fmaxf(ta[2], ta[3]));
        t = fmaxf(t, __shfl_xor(t, 16));
        t = fmaxf(t, __shfl_xor(t, 32));
        // defer-max: keep old reference max unless growth exceeds 8
        // (P values then bounded by 2^8=256 -- fine in bf16/f32).
        bool skip = __all(t - mrun[mB] <= 8.0f);
        resc[mB] = !skip;
        float mn = skip ? mrun[mB] : fmaxf(mrun[mB], t);
#pragma unroll
        for (int a = 0; a < 4; a++) {
#pragma unroll
          for (int j = 0; j < 4; j++) p[mB][a][j] = exp2_hw(p[mB][a][j] - mn);
          sa[a] = (p[mB][a][0] + p[mB][a][1]) + (p[mB][a][2] + p[mB][a][3]);
        }
        float rs = (sa[0] + sa[1]) + (sa[2] + sa[3]);
        rs += __shfl_xor(rs, 16);
        rs += __shfl_xor(rs, 32);
        if (skip) {
          lrun[mB] += rs;
        } else {
          fac[mB] = exp2_hw(mrun[mB] - mn);
          lrun[mB] = lrun[mB] * fac[mB] + rs;
          mrun[mB] = mn;
        }
      }
      // ---- P -> Ps (packed b64 writes) ----
#pragma unroll
      for (int mB = 0; mB < 2; mB++)
#pragma unroll
        for (int a = 0; a < 4; a++) {
          bf16x4 pk = {(__bf16)p[mB][a][0], (__bf16)p[mB][a][1],
                       (__bf16)p[mB][a][2], (__bf16)p[mB][a][3]};
          *(bf16x4*)&Ps[w][mB * 16 + r16][a * 16 + g * 4] = pk;
        }
      // ---- redistribute fac to O layout, rescale (only when max moved) ----
#pragma unroll
      for (int mB = 0; mB < 2; mB++)
        if (resc[mB]) {  // wave-uniform
          float fj[4];
#pragma unroll
          for (int j = 0; j < 4; j++) fj[j] = __shfl(fac[mB], g * 4 + j);
#pragma unroll
          for (int c = 0; c < 4; c++)
#pragma unroll
            for (int j = 0; j < 4; j++) o[mB][c][j] *= fj[j];
        }
      asm volatile("s_waitcnt lgkmcnt(0)" ::: "memory");
      bf16x8 pa[2][2];
#pragma unroll
      for (int m = 0; m < 2; m++)
#pragma unroll
        for (int h2 = 0; h2 < 2; h2++)
          pa[m][h2] = *(bf16x8*)&Ps[w][m * 16 + r16][h2 * 32 + g * 8];
      // ---- O += P V ----
      __builtin_amdgcn_s_setprio(1);
#pragma unroll
      for (int c = 0; c < 4; c++) {
        int vr = c * 16 + r16;
#pragma unroll
        for (int h2 = 0; h2 < 2; h2++) {
          bf16x8 vb = *(bf16x8*)&Vs[cur][vr * 64 + (((4 * h2 + g) ^ (vr & 7)) << 3)];
          o[0][c] = mfma16(pa[0][h2], vb, o[0][c]);
          o[1][c] = mfma16(pa[1][h2], vb, o[1][c]);
        }
      }
      __builtin_amdgcn_s_setprio(0);
    }
    __syncthreads();
  }

  // ---- epilogue: divide by l (redistributed), store ----
  float linv[2];
#pragma unroll
  for (int mB = 0; mB < 2; mB++) linv[mB] = 1.0f / lrun[mB];
  float li[2][4];
#pragma unroll
  for (int j = 0; j < 4; j++) {
    li[0][j] = __shfl(linv[0], g * 4 + j);
    li[1][j] = __shfl(linv[1], g * 4 + j);
  }
#pragma unroll
  for (int m = 0; m < 2; m++)
#pragma unroll
    for (int c = 0; c < 4; c++)
#pragma unroll
      for (int j = 0; j < 4; j++) {
        int q = qw0 + m * 16 + g * 4 + j, d = c * 16 + r16;
        ctx[((size_t)(b * TT + q)) * DK + h * HD + d] = (bf16_t)(o[m][c][j] * li[m][j]);
      }
}

// ---------------------------------------------------------------------------
extern "C" void kernel_launch(void* const* d_in, const int* in_sizes, int n_in,
                              void* d_out, int out_size, void* d_ws, size_t ws_size,
                              hipStream_t stream) {
  const float* x = (const float*)d_in[0];
  const float* Wq = (const float*)d_in[1];
  const float* Wk = (const float*)d_in[2];
  const float* Wv = (const float*)d_in[3];
  const float* Wo = (const float*)d_in[4];
  const float* bo = (const float*)d_in[5];
  float* out = (float*)d_out;

  char* ws = (char*)d_ws;
  const size_t MB = 1u << 20;
  bf16_t* xb    = (bf16_t*)(ws + 0 * MB);    // 16 MB
  bf16_t* Wqkvt = (bf16_t*)(ws + 16 * MB);   // 6 MB: [3][1024][1024] N-major
  bf16_t* Wot   = (bf16_t*)(ws + 22 * MB);   // 2 MB
  bf16_t* Qb    = (bf16_t*)(ws + 24 * MB);   // 16 MB [b,h,t,d] (pre-scaled)
  bf16_t* Kb    = (bf16_t*)(ws + 40 * MB);   // 16 MB [b,h,t,d]
  bf16_t* Vtb   = (bf16_t*)(ws + 56 * MB);   // 16 MB [b,h,d,t]
  bf16_t* ctx   = (bf16_t*)(ws + 72 * MB);   // 16 MB [b,t,h*64+d]

  const int M = BB * TT;  // 8192

  cast_x_kernel<<<(M * DK / 8 + 255) / 256, 256, 0, stream>>>(x, xb, M * DK / 8);

  transpose_cast4_kernel<<<dim3(32, 32, 4), dim3(32, 8), 0, stream>>>(
      Wq, Wk, Wv, Wo, Wqkvt, Wot);

  // fused QKV: 8192 x 3072 x 1024
  gemm_bt<0><<<dim3(3 * DK / 128, M / 128), 256, 0, stream>>>(
      xb, Wqkvt, Qb, Kb, Vtb, nullptr, M, 3 * DK, DK);

  attn_fwd<<<1024, 256, 0, stream>>>(Qb, Kb, Vtb, ctx);

  gemm_bt<2><<<dim3(DK / 128, M / 128), 256, 0, stream>>>(
      ctx, Wot, out, nullptr, nullptr, bo, M, DK, DK);
}